// Round 11
// baseline (267.116 us; speedup 1.0000x reference)
//
#include <hip/hip_runtime.h>
#include <stdint.h>

typedef __attribute__((ext_vector_type(8))) short short8;
typedef __attribute__((ext_vector_type(4))) float f32x4;
typedef unsigned short u16;

#define VMCNT4() asm volatile("s_waitcnt vmcnt(4)" ::: "memory")
#define VMCNT0() asm volatile("s_waitcnt vmcnt(0)" ::: "memory")
#define SBAR() do { __builtin_amdgcn_sched_barrier(0); \
                    __builtin_amdgcn_s_barrier(); \
                    __builtin_amdgcn_sched_barrier(0); } while (0)

__device__ __forceinline__ u16 f2bf(float f) {
  union { float f; uint32_t u; } v; v.f = f;
  return (u16)((v.u + 0x7FFFu + ((v.u >> 16) & 1u)) >> 16);
}
__device__ __forceinline__ float bf2f(u16 u) {
  union { uint32_t u; float f; } v; v.u = (uint32_t)u << 16; return v.f;
}

__device__ __forceinline__ void gl_lds16(const void* g, void* l) {
  __builtin_amdgcn_global_load_lds(
      (const __attribute__((address_space(1))) void*)g,
      (__attribute__((address_space(3))) void*)l, 16, 0, 0);
}

// ---------------- unified GEMM: dbuf + counted-vmcnt pipeline ----------------
// C[M,N] = A[M,K](bf16) @ B[N,K](bf16)^T (+bias1+bias2); f32 and/or bf16 out.
// Pipeline: STAGE(t+2) issued after read-barrier of t; vmcnt(4) (counted, not
// drain-0) guarantees tile t+1 landed; write-barrier publishes it.
__global__ __launch_bounds__(256) void gemm_bt(
    const u16* __restrict__ A, const u16* __restrict__ B,
    float* __restrict__ Cf, u16* __restrict__ Cb,
    const float* __restrict__ bias1, const float* __restrict__ bias2,
    int M, int N, int K)
{
  __shared__ __align__(16) u16 As[2][128 * 32];
  __shared__ __align__(16) u16 Bs[2][128 * 32];
  const int t = threadIdx.x;
  const int lane = t & 63;
  const int w = t >> 6;
  const int wr = w >> 1, wc = w & 1;
  const int m0 = blockIdx.y * 128, n0 = blockIdx.x * 128;
  const int lr = lane & 15;
  const int lk = (lane >> 4) * 8;
  const int srow = t >> 2;
  const int scol = (t & 3) * 8;

  // Bias for this lane's epilogue columns, loaded and DRAINED before the
  // pipeline starts so the counted vmcnt(4) waits below are exact.
  float bs[4];
#pragma unroll
  for (int n = 0; n < 4; ++n) {
    int col = n0 + wc * 64 + n * 16 + lr;
    float v = 0.f;
    if (bias1) v += bias1[col];
    if (bias2) v += bias2[col];
    bs[n] = v;
  }
  VMCNT0();

  const u16* gA = A + (size_t)(m0 + srow) * K + scol;
  const u16* gB = B + (size_t)(n0 + srow) * K + scol;
  const int nt = K >> 5;

  // stage one 128x32 K-tile pair into buffer `buf`; advances gA/gB
  auto STAGE = [&](int buf) {
    gl_lds16(gA,                 As[buf] + t * 8);
    gl_lds16(gA + (size_t)64 * K, As[buf] + 2048 + t * 8);
    gl_lds16(gB,                 Bs[buf] + t * 8);
    gl_lds16(gB + (size_t)64 * K, Bs[buf] + 2048 + t * 8);
    gA += 32; gB += 32;
  };

  f32x4 acc[4][4] = {};

  STAGE(0);
  STAGE(1);
  VMCNT4();   // own 4 loads of tile0 landed (4 of tile1 still in flight)
  SBAR();     // all waves' tile0 landed

  for (int tt = 0; tt < nt; ++tt) {
    const int cur = tt & 1;
    short8 a[4], b[4];
#pragma unroll
    for (int m = 0; m < 4; ++m)
      a[m] = *(const short8*)(As[cur] + (wr * 64 + m * 16 + lr) * 32 + lk);
#pragma unroll
    for (int n = 0; n < 4; ++n)
      b[n] = *(const short8*)(Bs[cur] + (wc * 64 + n * 16 + lr) * 32 + lk);
    __builtin_amdgcn_s_setprio(1);
#pragma unroll
    for (int m = 0; m < 4; ++m)
#pragma unroll
      for (int n = 0; n < 4; ++n)
        acc[m][n] = __builtin_amdgcn_mfma_f32_16x16x32_bf16(a[m], b[n], acc[m][n], 0, 0, 0);
    __builtin_amdgcn_s_setprio(0);
    SBAR();                                  // (R) all waves done reading buf[cur]
    if (tt + 2 < nt) { STAGE(cur); VMCNT4(); }   // tile t+1 landed; t+2 in flight
    else             { VMCNT0(); }               // tail: drain
    SBAR();                                  // (W) next buffer published
  }

#pragma unroll
  for (int n = 0; n < 4; ++n) {
    int col = n0 + wc * 64 + n * 16 + lr;
#pragma unroll
    for (int m = 0; m < 4; ++m) {
#pragma unroll
      for (int r = 0; r < 4; ++r) {
        int row = m0 + wr * 64 + m * 16 + (lane >> 4) * 4 + r;
        float vv = acc[m][n][r] + bs[n];
        if (Cf) Cf[(size_t)row * N + col] = vv;
        if (Cb) Cb[(size_t)row * N + col] = f2bf(vv);
      }
    }
  }
}

// ---------------- dedicated attention partial: rows 1..63, online softmax ----
// 512 blocks x 4 waves, 1 batch per wave, quad-row streaming, nt loads.
__global__ __launch_bounds__(256) void attn_k(
    const float* __restrict__ Qk, const float* __restrict__ mem,
    float* __restrict__ attst)
{
  const int t = threadIdx.x;
  const int lane = t & 63;
  const int b = blockIdx.x * 4 + (t >> 6);          // 0..2047
  const float* q = Qk + (size_t)b * 1024;
  f32x4 qv[4];
#pragma unroll
  for (int i = 0; i < 4; ++i)
    qv[i] = *(const f32x4*)(q + (i * 64 + lane) * 4);
  const float* mb = mem + (size_t)b * 65536;

  float m_run = -3e38f, l = 0.f;
  f32x4 cx[4] = {};

  // 15 quads: rows 1..60
  for (int qd = 0; qd < 15; ++qd) {
    const float* r0 = mb + (size_t)(1 + qd * 4) * 1024;
    f32x4 rv[4][4];
    float s[4] = {0.f, 0.f, 0.f, 0.f};
#pragma unroll
    for (int rr = 0; rr < 4; ++rr)
#pragma unroll
      for (int i = 0; i < 4; ++i) {
        rv[rr][i] = __builtin_nontemporal_load(
            (const f32x4*)(r0 + rr * 1024 + (i * 64 + lane) * 4));
        s[rr] += rv[rr][i][0] * qv[i][0] + rv[rr][i][1] * qv[i][1] +
                 rv[rr][i][2] * qv[i][2] + rv[rr][i][3] * qv[i][3];
      }
#pragma unroll
    for (int rr = 0; rr < 4; ++rr) {
#pragma unroll
      for (int off = 32; off; off >>= 1) s[rr] += __shfl_xor(s[rr], off);
      s[rr] *= 0.03125f;
    }
#pragma unroll
    for (int rr = 0; rr < 4; ++rr) {
      if (s[rr] <= m_run + 8.f) {        // defer-max: common path
        float e = __expf(s[rr] - m_run);
        l += e;
#pragma unroll
        for (int i = 0; i < 4; ++i) cx[i] += rv[rr][i] * e;
      } else {
        float sc = __expf(m_run - s[rr]);
        m_run = s[rr];
        l = l * sc + 1.f;
#pragma unroll
        for (int i = 0; i < 4; ++i) cx[i] = cx[i] * sc + rv[rr][i];
      }
    }
  }
  // rows 61..63 singles
  for (int r = 61; r <= 63; ++r) {
    const float* row = mb + (size_t)r * 1024;
    f32x4 rv[4];
    float s = 0.f;
#pragma unroll
    for (int i = 0; i < 4; ++i) {
      rv[i] = __builtin_nontemporal_load(
          (const f32x4*)(row + (i * 64 + lane) * 4));
      s += rv[i][0] * qv[i][0] + rv[i][1] * qv[i][1] +
           rv[i][2] * qv[i][2] + rv[i][3] * qv[i][3];
    }
#pragma unroll
    for (int off = 32; off; off >>= 1) s += __shfl_xor(s, off);
    s *= 0.03125f;
    if (s <= m_run + 8.f) {
      float e = __expf(s - m_run);
      l += e;
#pragma unroll
      for (int i = 0; i < 4; ++i) cx[i] += rv[i] * e;
    } else {
      float sc = __expf(m_run - s);
      m_run = s;
      l = l * sc + 1.f;
#pragma unroll
      for (int i = 0; i < 4; ++i) cx[i] = cx[i] * sc + rv[i];
    }
  }
  // store state
  float* st = attst + (size_t)b * 1032;
#pragma unroll
  for (int i = 0; i < 4; ++i)
    *(f32x4*)(st + (i * 64 + lane) * 4) = cx[i];
  if (lane == 0) { st[1024] = m_run; st[1025] = l; }
}

// ---------------- prep: all f32->bf16 packs + Wq/Wk transposes ----------------
__global__ __launch_bounds__(256) void prep_k(
    const float* __restrict__ pose, const float* __restrict__ h,
    const float* __restrict__ W_ih, const float* __restrict__ W_hh,
    const float* __restrict__ query, const float* __restrict__ Wv,
    const float* __restrict__ Wq, const float* __restrict__ Wk,
    u16* __restrict__ xcat, u16* __restrict__ wcat,
    u16* __restrict__ qry, u16* __restrict__ wvb,
    u16* __restrict__ wqtb, u16* __restrict__ wktb)
{
  __shared__ u16 tile[64][65];
  int blk = blockIdx.x;
  int t = threadIdx.x;
  if (blk >= 15360) {  // transpose-convert: dst[n*1024+a] = bf16(src[a*1024+n])
    const float* src; u16* dst; int tblk;
    if (blk < 15616) { src = Wq; dst = wqtb; tblk = blk - 15360; }
    else             { src = Wk; dst = wktb; tblk = blk - 15616; }
    int tr = (tblk >> 4) * 64, tc = (tblk & 15) * 64;
    int tx = t & 63;
    int ty = (t >> 6) * 16;
#pragma unroll
    for (int i = 0; i < 16; ++i)
      tile[ty + i][tx] = f2bf(src[(size_t)(tr + ty + i) * 1024 + tc + tx]);
    __syncthreads();
#pragma unroll
    for (int i = 0; i < 16; ++i)
      dst[(size_t)(tc + ty + i) * 1024 + tr + tx] = tile[tx][ty + i];
    return;
  }
  const float* src; u16* dst; int ostride, ooff, base;
  if (blk < 2048)       { src = pose;  dst = xcat; ostride = 2048; ooff = 0;    base = 0; }
  else if (blk < 4096)  { src = h;     dst = xcat; ostride = 2048; ooff = 1024; base = 2048; }
  else if (blk < 8192)  { src = W_ih;  dst = wcat; ostride = 2048; ooff = 0;    base = 4096; }
  else if (blk < 12288) { src = W_hh;  dst = wcat; ostride = 2048; ooff = 1024; base = 8192; }
  else if (blk < 14336) { src = query; dst = qry;  ostride = 1024; ooff = 0;    base = 12288; }
  else                  { src = Wv;    dst = wvb;  ostride = 1024; ooff = 0;    base = 14336; }
  int r = blk - base;
  int cc = t * 4;
  float4 v = *(const float4*)(src + (size_t)r * 1024 + cc);
  ushort4 o; o.x = f2bf(v.x); o.y = f2bf(v.y); o.z = f2bf(v.z); o.w = f2bf(v.w);
  *(ushort4*)(dst + (size_t)r * ostride + ooff + cc) = o;
}

// qkb[n] += partial of bq @ Wk (qkb pre-zeroed via memset)
__global__ __launch_bounds__(256) void bqwk_k(
    const float* __restrict__ bq, const float* __restrict__ Wk,
    float* __restrict__ qkb)
{
  int n = blockIdx.x * 256 + threadIdx.x;
  int j0 = blockIdx.y * 64;
  float s = 0.f;
#pragma unroll 8
  for (int j = j0; j < j0 + 64; ++j) s += bq[j] * Wk[(size_t)j * 1024 + n];
  atomicAdd(&qkb[n], s);
}

// ---------------- fused LSTM elementwise + attention finish ----------------
__global__ __launch_bounds__(256) void lstmfin_k(
    const u16* __restrict__ gates, const float* __restrict__ c,
    const float* __restrict__ Qk, const float* __restrict__ attst,
    float* __restrict__ out_h, float* __restrict__ out_c,
    u16* __restrict__ ctxb)
{
  const int b = blockIdx.x;
  const int t = threadIdx.x;
  const int lane = t & 63, wv_id = t >> 6;
  const int p = t * 4;
  const u16* g = gates + (size_t)b * 4096;
  ushort4 igu = *(const ushort4*)(g + p);
  ushort4 fgu = *(const ushort4*)(g + 1024 + p);
  ushort4 ggu = *(const ushort4*)(g + 2048 + p);
  ushort4 ogu = *(const ushort4*)(g + 3072 + p);
  float4 cv = *(const float4*)(c + (size_t)b * 1024 + p);

  float hn[4], cn[4];
  {
    float igs[4] = {bf2f(igu.x), bf2f(igu.y), bf2f(igu.z), bf2f(igu.w)};
    float fgs[4] = {bf2f(fgu.x), bf2f(fgu.y), bf2f(fgu.z), bf2f(fgu.w)};
    float ggs[4] = {bf2f(ggu.x), bf2f(ggu.y), bf2f(ggu.z), bf2f(ggu.w)};
    float ogs[4] = {bf2f(ogu.x), bf2f(ogu.y), bf2f(ogu.z), bf2f(ogu.w)};
    float cvs[4] = {cv.x, cv.y, cv.z, cv.w};
#pragma unroll
    for (int j = 0; j < 4; ++j) {
      float si = 1.f / (1.f + __expf(-igs[j]));
      float sf = 1.f / (1.f + __expf(-fgs[j]));
      float so = 1.f / (1.f + __expf(-ogs[j]));
      float tg = 2.f / (1.f + __expf(-2.f * ggs[j])) - 1.f;
      cn[j] = sf * cvs[j] + si * tg;
      float tc2 = 2.f / (1.f + __expf(-2.f * cn[j])) - 1.f;
      hn[j] = so * tc2;
    }
  }
  *(float4*)(out_c + (size_t)b * 1024 + p) = make_float4(cn[0], cn[1], cn[2], cn[3]);
  *(float4*)(out_h + (size_t)b * 1024 + p) = make_float4(hn[0], hn[1], hn[2], hn[3]);

  // s_last = dot(Qk[b], h_new[b]) / 32  (block reduction)
  float4 qv = *(const float4*)(Qk + (size_t)b * 1024 + p);
  float part = qv.x * hn[0] + qv.y * hn[1] + qv.z * hn[2] + qv.w * hn[3];
#pragma unroll
  for (int off = 32; off; off >>= 1) part += __shfl_xor(part, off);
  __shared__ float red[4];
  if (lane == 0) red[wv_id] = part;
  __syncthreads();
  float s_last = (red[0] + red[1] + red[2] + red[3]) * 0.03125f;

  const float* st = attst + (size_t)b * 1032;
  float m_run = st[1024], l = st[1025];
  float4 cx = *(const float4*)(st + p);
  if (s_last <= m_run + 8.f) {
    float e = __expf(s_last - m_run);
    l += e;
    cx.x += e * hn[0]; cx.y += e * hn[1]; cx.z += e * hn[2]; cx.w += e * hn[3];
  } else {
    float sc = __expf(m_run - s_last);
    l = l * sc + 1.f;
    cx.x = cx.x * sc + hn[0]; cx.y = cx.y * sc + hn[1];
    cx.z = cx.z * sc + hn[2]; cx.w = cx.w * sc + hn[3];
  }
  float inv = 1.f / l;
  ushort4 o;
  o.x = f2bf(cx.x * inv); o.y = f2bf(cx.y * inv);
  o.z = f2bf(cx.z * inv); o.w = f2bf(cx.w * inv);
  *(ushort4*)(ctxb + (size_t)b * 1024 + p) = o;
}

extern "C" void kernel_launch(void* const* d_in, const int* in_sizes, int n_in,
                              void* d_out, int out_size, void* d_ws, size_t ws_size,
                              hipStream_t stream) {
  const int Bb = 2048, Hh = 1024;
  const float* pose  = (const float*)d_in[0];
  const float* query = (const float*)d_in[1];
  const float* h     = (const float*)d_in[2];
  const float* c     = (const float*)d_in[3];
  const float* mem   = (const float*)d_in[4];
  const float* W_ih  = (const float*)d_in[5];
  const float* W_hh  = (const float*)d_in[6];
  const float* b_ih  = (const float*)d_in[7];
  const float* b_hh  = (const float*)d_in[8];
  const float* Wq    = (const float*)d_in[9];
  const float* bq    = (const float*)d_in[10];
  const float* Wk    = (const float*)d_in[11];
  // d_in[12] = bk: m-independent score shift, cancels in softmax
  const float* Wv    = (const float*)d_in[13];
  const float* bv    = (const float*)d_in[14];

  float* out_att = (float*)d_out;
  float* out_h   = out_att + (size_t)Bb * Hh;
  float* out_c   = out_h + (size_t)Bb * Hh;

  char* wp = (char*)d_ws;
  auto alloc = [&](size_t bytes) {
    char* p = wp; wp += (bytes + 255) & ~(size_t)255; return p;
  };
  u16*   Xcat  = (u16*)alloc((size_t)2048 * 2048 * 2);   // 8 MB
  u16*   Wcat  = (u16*)alloc((size_t)4096 * 2048 * 2);   // 16 MB
  // next 4 contiguous, all dead before attn -> attst aliases them
  u16*   Qryb  = (u16*)alloc((size_t)2048 * 1024 * 2);   // 4 MB
  u16*   WqTb  = (u16*)alloc((size_t)1024 * 1024 * 2);   // 2 MB
  u16*   WkTb  = (u16*)alloc((size_t)1024 * 1024 * 2);   // 2 MB
  u16*   Gb    = (u16*)alloc((size_t)1024 * 1024 * 2);   // 2 MB
  u16*   Wvb   = (u16*)alloc((size_t)1024 * 1024 * 2);   // 2 MB (live through final)
  u16*   gates = (u16*)alloc((size_t)2048 * 4096 * 2);   // 16 MB (bf16)
  float* qkb   = (float*)alloc((size_t)1024 * 4);
  float* Qk    = (float*)alloc((size_t)2048 * 1024 * 4); // 8 MB
  u16*   ctxb  = (u16*)alloc((size_t)2048 * 1024 * 2);   // 4 MB
  float* attst = (float*)Qryb;   // [2048][1032] f32 = 8.45 MB < 10 MB alias pool

  // 1. all conversions in one kernel
  prep_k<<<15872, 256, 0, stream>>>(pose, h, W_ih, W_hh, query, Wv, Wq, Wk,
                                    Xcat, Wcat, Qryb, Wvb, WqTb, WkTb);

  // 2. qkb = bq @ Wk (tiny)
  hipMemsetAsync(qkb, 0, 1024 * sizeof(float), stream);
  bqwk_k<<<dim3(4, 16), 256, 0, stream>>>(bq, Wk, qkb);

  // 3. G[n,j] = sum_a Wk[a,n]*Wq[a,j]  (query @ G^T == (query@Wq^T)@Wk)
  gemm_bt<<<dim3(8, 8), 256, 0, stream>>>(
      WkTb, WqTb, nullptr, Gb, nullptr, nullptr, 1024, 1024, 1024);

  // 4. Qk = query @ G^T + bq@Wk
  gemm_bt<<<dim3(8, 16), 256, 0, stream>>>(
      Qryb, Gb, Qk, nullptr, qkb, nullptr, 2048, 1024, 1024);

  // 5. gates = [pose|h] @ [W_ih|W_hh]^T + b_ih + b_hh  (bf16 out)
  gemm_bt<<<dim3(32, 16), 256, 0, stream>>>(
      Xcat, Wcat, nullptr, gates, b_ih, b_hh, 2048, 4096, 2048);

  // 6. attention partial solo (full-GPU streaming: 2048 waves)
  attn_k<<<512, 256, 0, stream>>>(Qk, mem, attst);

  // 7. LSTM elementwise + attention finish (h_new row) -> ctx bf16
  lstmfin_k<<<2048, 256, 0, stream>>>(gates, c, Qk, attst, out_h, out_c, ctxb);

  // 8. attended = ctx @ Wv^T + bv
  gemm_bt<<<dim3(8, 16), 256, 0, stream>>>(
      ctxb, Wvb, out_att, nullptr, bv, nullptr, 2048, 1024, 1024);
}

// Round 12
// 248.418 us; speedup vs baseline: 1.0753x; 1.0753x over previous
//
#include <hip/hip_runtime.h>
#include <stdint.h>

typedef __attribute__((ext_vector_type(8))) short short8;
typedef __attribute__((ext_vector_type(4))) float f32x4;
typedef unsigned short u16;

#define SBAR() do { __builtin_amdgcn_sched_barrier(0); \
                    __builtin_amdgcn_s_barrier(); \
                    __builtin_amdgcn_sched_barrier(0); } while (0)

__device__ __forceinline__ u16 f2bf(float f) {
  union { float f; uint32_t u; } v; v.f = f;
  return (u16)((v.u + 0x7FFFu + ((v.u >> 16) & 1u)) >> 16);
}
__device__ __forceinline__ float bf2f(u16 u) {
  union { uint32_t u; float f; } v; v.u = (uint32_t)u << 16; return v.f;
}

__device__ __forceinline__ void gl_lds16(const void* g, void* l) {
  __builtin_amdgcn_global_load_lds(
      (const __attribute__((address_space(1))) void*)g,
      (__attribute__((address_space(3))) void*)l, 16, 0, 0);
}

// ---------------- generic GEMM (R8 plain m97 structure, 128x128) -------------
__global__ __launch_bounds__(256) void gemm_bt(
    const u16* __restrict__ A, const u16* __restrict__ B,
    float* __restrict__ Cf, u16* __restrict__ Cb,
    const float* __restrict__ bias1,
    int M, int N, int K)
{
  __shared__ __align__(16) u16 As[128 * 32];
  __shared__ __align__(16) u16 Bs[128 * 32];
  const int t = threadIdx.x;
  const int lane = t & 63;
  const int w = t >> 6;
  const int wr = w >> 1, wc = w & 1;
  const int m0 = blockIdx.y * 128, n0 = blockIdx.x * 128;
  const int lr = lane & 15;
  const int lk = (lane >> 4) * 8;
  const int srow = t >> 2;
  const int scol = (t & 3) * 8;

  const u16* gA = A + (size_t)(m0 + srow) * K + scol;
  const u16* gB = B + (size_t)(n0 + srow) * K + scol;

  f32x4 acc[4][4] = {};

  for (int k0 = 0; k0 < K; k0 += 32) {
    gl_lds16(gA,                  As + t * 8);
    gl_lds16(gA + (size_t)64 * K, As + 2048 + t * 8);
    gl_lds16(gB,                  Bs + t * 8);
    gl_lds16(gB + (size_t)64 * K, Bs + 2048 + t * 8);
    gA += 32; gB += 32;
    __syncthreads();

    short8 a[4], b[4];
#pragma unroll
    for (int m = 0; m < 4; ++m)
      a[m] = *(const short8*)(As + (wr * 64 + m * 16 + lr) * 32 + lk);
#pragma unroll
    for (int n = 0; n < 4; ++n)
      b[n] = *(const short8*)(Bs + (wc * 64 + n * 16 + lr) * 32 + lk);
#pragma unroll
    for (int m = 0; m < 4; ++m)
#pragma unroll
      for (int n = 0; n < 4; ++n)
        acc[m][n] = __builtin_amdgcn_mfma_f32_16x16x32_bf16(a[m], b[n], acc[m][n], 0, 0, 0);
    __syncthreads();
  }

#pragma unroll
  for (int n = 0; n < 4; ++n) {
    int col = n0 + wc * 64 + n * 16 + lr;
    float bsum = bias1 ? bias1[col] : 0.f;
#pragma unroll
    for (int m = 0; m < 4; ++m) {
#pragma unroll
      for (int r = 0; r < 4; ++r) {
        int row = m0 + wr * 64 + m * 16 + (lane >> 4) * 4 + r;
        float vv = acc[m][n][r] + bsum;
        if (Cf) Cf[(size_t)row * N + col] = vv;
        if (Cb) Cb[(size_t)row * N + col] = f2bf(vv);
      }
    }
  }
}

// ---------------- gates GEMM: 256x256, BK=64, 8-wave, counted-vmcnt ----------
// K-split x2 -> 256 blocks x 512 threads, 128KB LDS, 1 block/CU.
// LDS layout (bytes): buf*65536 + mat*32768 + half*16384 + row128*128 + cb.
// st_16x32 swizzle involution on cb: cb ^= ((row>>2)&1)<<5 — applied on BOTH
// the staging source (pre-swizzled global col) and the ds_read address.
__global__ __launch_bounds__(512) void gates8_k(
    const u16* __restrict__ Xcat, const u16* __restrict__ Wcat,
    u16* __restrict__ gparts)
{
  __shared__ __align__(16) u16 lds[65536];     // 128 KB
  const int t = threadIdx.x;                   // 0..511
  const int l = t & 63;
  const int w = t >> 6;                        // 0..7
  const int wr = w >> 2, wc = w & 3;           // 2M x 4N wave grid
  const int bid = blockIdx.x;
  const int tile = bid >> 1, khalf = bid & 1;
  const int m0 = (tile >> 4) * 256;            // 8 m-tiles
  const int n0 = (tile & 15) * 256;            // 16 n-tiles
  const int lr = l & 15;
  const int l4 = l >> 4;                       // 0..3

  // staging: lane l covers LDS chunk offset l*16; pre-swizzled global col:
  // rows-in-chunk = (l>>3); col elems = (l&7)*8 ^ ((l>=32)<<4)  [bit9->bit5 inv]
  const int sr = l >> 3;
  const int sc = ((l & 7) * 8) ^ ((l >> 5) << 4);

  const u16* Abase = Xcat + (size_t)m0 * 2048 + khalf * 1024 + sc;
  const u16* Bbase = Wcat + (size_t)n0 * 2048 + khalf * 1024 + sc;

  #define STAGE(buf, kt) do {                                                  \
    const int kof_ = (kt) * 64;                                                \
    _Pragma("unroll")                                                          \
    for (int hh = 0; hh < 2; ++hh)                                             \
      _Pragma("unroll")                                                        \
      for (int j = 0; j < 2; ++j) {                                            \
        int row_ = hh * 128 + (w + 8 * j) * 8 + sr;                            \
        char* dA = (char*)lds + (buf) * 65536 + hh * 16384 + (w + 8*j) * 1024 + l * 16; \
        char* dB = dA + 32768;                                                 \
        gl_lds16(Abase + (size_t)row_ * 2048 + kof_, dA);                      \
        gl_lds16(Bbase + (size_t)row_ * 2048 + kof_, dB);                      \
      }                                                                        \
  } while (0)

  // frag reads (swizzled)
  auto LDA = [&](int buf, int mf, int s) -> short8 {
    int rr = mf * 16 + lr;
    int cb = (s * 64 + l4 * 16) ^ (((rr >> 2) & 1) << 5);
    return *(const short8*)((const char*)lds + buf * 65536 + wr * 16384 + rr * 128 + cb);
  };
  auto LDB = [&](int buf, int nf, int s) -> short8 {
    int rr = (wc & 1) * 64 + nf * 16 + lr;
    int cb = (s * 64 + l4 * 16) ^ (((rr >> 2) & 1) << 5);
    return *(const short8*)((const char*)lds + buf * 65536 + 32768 + (wc >> 1) * 16384 + rr * 128 + cb);
  };

  f32x4 acc[8][4] = {};

  STAGE(0, 0);
  STAGE(1, 1);
  asm volatile("s_waitcnt vmcnt(8)" ::: "memory");   // tile0's 8 loads landed
  SBAR();

  for (int kt = 0; kt < 16; ++kt) {
    const int cur = kt & 1;
    short8 a0[4][2], a1[4][2], b[2][2];
    // Q(0,0): m-frags 0..3 x n-frags 0..1
#pragma unroll
    for (int i = 0; i < 4; ++i) { a0[i][0] = LDA(cur, i, 0); a0[i][1] = LDA(cur, i, 1); }
#pragma unroll
    for (int n = 0; n < 2; ++n) { b[n][0] = LDB(cur, n, 0); b[n][1] = LDB(cur, n, 1); }
    __builtin_amdgcn_s_setprio(1);
#pragma unroll
    for (int i = 0; i < 4; ++i)
#pragma unroll
      for (int n = 0; n < 2; ++n)
#pragma unroll
        for (int s = 0; s < 2; ++s)
          acc[i][n] = __builtin_amdgcn_mfma_f32_16x16x32_bf16(a0[i][s], b[n][s], acc[i][n], 0, 0, 0);
    __builtin_amdgcn_s_setprio(0);
    // Q(1,0): m-frags 4..7 x n-frags 0..1
#pragma unroll
    for (int i = 0; i < 4; ++i) { a1[i][0] = LDA(cur, 4 + i, 0); a1[i][1] = LDA(cur, 4 + i, 1); }
    __builtin_amdgcn_s_setprio(1);
#pragma unroll
    for (int i = 0; i < 4; ++i)
#pragma unroll
      for (int n = 0; n < 2; ++n)
#pragma unroll
        for (int s = 0; s < 2; ++s)
          acc[4 + i][n] = __builtin_amdgcn_mfma_f32_16x16x32_bf16(a1[i][s], b[n][s], acc[4 + i][n], 0, 0, 0);
    __builtin_amdgcn_s_setprio(0);
    // Q(1,1) then Q(0,1): n-frags 2..3 (a1 then a0 still live)
#pragma unroll
    for (int n = 0; n < 2; ++n) { b[n][0] = LDB(cur, 2 + n, 0); b[n][1] = LDB(cur, 2 + n, 1); }
    __builtin_amdgcn_s_setprio(1);
#pragma unroll
    for (int i = 0; i < 4; ++i)
#pragma unroll
      for (int n = 0; n < 2; ++n)
#pragma unroll
        for (int s = 0; s < 2; ++s)
          acc[4 + i][2 + n] = __builtin_amdgcn_mfma_f32_16x16x32_bf16(a1[i][s], b[n][s], acc[4 + i][2 + n], 0, 0, 0);
#pragma unroll
    for (int i = 0; i < 4; ++i)
#pragma unroll
      for (int n = 0; n < 2; ++n)
#pragma unroll
        for (int s = 0; s < 2; ++s)
          acc[i][2 + n] = __builtin_amdgcn_mfma_f32_16x16x32_bf16(a0[i][s], b[n][s], acc[i][2 + n], 0, 0, 0);
    __builtin_amdgcn_s_setprio(0);

    SBAR();                                   // all waves done reading buf[cur]
    if (kt + 2 < 16) {
      STAGE(cur, kt + 2);                     // 8 loads into freed buffer
      asm volatile("s_waitcnt vmcnt(8)" ::: "memory");  // tile kt+1 landed
    } else {
      asm volatile("s_waitcnt vmcnt(0)" ::: "memory");  // tail drain
    }
    SBAR();                                   // publish
  }
  #undef STAGE

  u16* out = gparts + (size_t)khalf * 2048 * 4096;
#pragma unroll
  for (int nf = 0; nf < 4; ++nf) {
    int col = n0 + wc * 64 + nf * 16 + lr;
#pragma unroll
    for (int mf = 0; mf < 8; ++mf)
#pragma unroll
      for (int r = 0; r < 4; ++r) {
        int row = m0 + wr * 128 + mf * 16 + l4 * 4 + r;
        out[(size_t)row * 4096 + col] = f2bf(acc[mf][nf][r]);
      }
  }
}

// ---------------- dedicated attention partial: rows 1..63, online softmax ----
__global__ __launch_bounds__(256) void attn_k(
    const float* __restrict__ Qk, const float* __restrict__ mem,
    float* __restrict__ attst)
{
  const int t = threadIdx.x;
  const int lane = t & 63;
  const int b = blockIdx.x * 4 + (t >> 6);
  const float* q = Qk + (size_t)b * 1024;
  f32x4 qv[4];
#pragma unroll
  for (int i = 0; i < 4; ++i)
    qv[i] = *(const f32x4*)(q + (i * 64 + lane) * 4);
  const float* mb = mem + (size_t)b * 65536;

  float m_run = -3e38f, l = 0.f;
  f32x4 cx[4] = {};

  for (int qd = 0; qd < 15; ++qd) {
    const float* r0 = mb + (size_t)(1 + qd * 4) * 1024;
    f32x4 rv[4][4];
    float s[4] = {0.f, 0.f, 0.f, 0.f};
#pragma unroll
    for (int rr = 0; rr < 4; ++rr)
#pragma unroll
      for (int i = 0; i < 4; ++i) {
        rv[rr][i] = __builtin_nontemporal_load(
            (const f32x4*)(r0 + rr * 1024 + (i * 64 + lane) * 4));
        s[rr] += rv[rr][i][0] * qv[i][0] + rv[rr][i][1] * qv[i][1] +
                 rv[rr][i][2] * qv[i][2] + rv[rr][i][3] * qv[i][3];
      }
#pragma unroll
    for (int rr = 0; rr < 4; ++rr) {
#pragma unroll
      for (int off = 32; off; off >>= 1) s[rr] += __shfl_xor(s[rr], off);
      s[rr] *= 0.03125f;
    }
#pragma unroll
    for (int rr = 0; rr < 4; ++rr) {
      if (s[rr] <= m_run + 8.f) {
        float e = __expf(s[rr] - m_run);
        l += e;
#pragma unroll
        for (int i = 0; i < 4; ++i) cx[i] += rv[rr][i] * e;
      } else {
        float sc = __expf(m_run - s[rr]);
        m_run = s[rr];
        l = l * sc + 1.f;
#pragma unroll
        for (int i = 0; i < 4; ++i) cx[i] = cx[i] * sc + rv[rr][i];
      }
    }
  }
  for (int r = 61; r <= 63; ++r) {
    const float* row = mb + (size_t)r * 1024;
    f32x4 rv[4];
    float s = 0.f;
#pragma unroll
    for (int i = 0; i < 4; ++i) {
      rv[i] = __builtin_nontemporal_load(
          (const f32x4*)(row + (i * 64 + lane) * 4));
      s += rv[i][0] * qv[i][0] + rv[i][1] * qv[i][1] +
           rv[i][2] * qv[i][2] + rv[i][3] * qv[i][3];
    }
#pragma unroll
    for (int off = 32; off; off >>= 1) s += __shfl_xor(s, off);
    s *= 0.03125f;
    if (s <= m_run + 8.f) {
      float e = __expf(s - m_run);
      l += e;
#pragma unroll
      for (int i = 0; i < 4; ++i) cx[i] += rv[i] * e;
    } else {
      float sc = __expf(m_run - s);
      m_run = s;
      l = l * sc + 1.f;
#pragma unroll
      for (int i = 0; i < 4; ++i) cx[i] = cx[i] * sc + rv[i];
    }
  }
  float* st = attst + (size_t)b * 1032;
#pragma unroll
  for (int i = 0; i < 4; ++i)
    *(f32x4*)(st + (i * 64 + lane) * 4) = cx[i];
  if (lane == 0) { st[1024] = m_run; st[1025] = l; }
}

// ---------------- prep: all f32->bf16 packs + Wq/Wk transposes ----------------
__global__ __launch_bounds__(256) void prep_k(
    const float* __restrict__ pose, const float* __restrict__ h,
    const float* __restrict__ W_ih, const float* __restrict__ W_hh,
    const float* __restrict__ query, const float* __restrict__ Wv,
    const float* __restrict__ Wq, const float* __restrict__ Wk,
    u16* __restrict__ xcat, u16* __restrict__ wcat,
    u16* __restrict__ qry, u16* __restrict__ wvb,
    u16* __restrict__ wqtb, u16* __restrict__ wktb)
{
  __shared__ u16 tile[64][65];
  int blk = blockIdx.x;
  int t = threadIdx.x;
  if (blk >= 15360) {
    const float* src; u16* dst; int tblk;
    if (blk < 15616) { src = Wq; dst = wqtb; tblk = blk - 15360; }
    else             { src = Wk; dst = wktb; tblk = blk - 15616; }
    int tr = (tblk >> 4) * 64, tc = (tblk & 15) * 64;
    int tx = t & 63;
    int ty = (t >> 6) * 16;
#pragma unroll
    for (int i = 0; i < 16; ++i)
      tile[ty + i][tx] = f2bf(src[(size_t)(tr + ty + i) * 1024 + tc + tx]);
    __syncthreads();
#pragma unroll
    for (int i = 0; i < 16; ++i)
      dst[(size_t)(tc + ty + i) * 1024 + tr + tx] = tile[tx][ty + i];
    return;
  }
  const float* src; u16* dst; int ostride, ooff, base;
  if (blk < 2048)       { src = pose;  dst = xcat; ostride = 2048; ooff = 0;    base = 0; }
  else if (blk < 4096)  { src = h;     dst = xcat; ostride = 2048; ooff = 1024; base = 2048; }
  else if (blk < 8192)  { src = W_ih;  dst = wcat; ostride = 2048; ooff = 0;    base = 4096; }
  else if (blk < 12288) { src = W_hh;  dst = wcat; ostride = 2048; ooff = 1024; base = 8192; }
  else if (blk < 14336) { src = query; dst = qry;  ostride = 1024; ooff = 0;    base = 12288; }
  else                  { src = Wv;    dst = wvb;  ostride = 1024; ooff = 0;    base = 14336; }
  int r = blk - base;
  int cc = t * 4;
  float4 v = *(const float4*)(src + (size_t)r * 1024 + cc);
  ushort4 o; o.x = f2bf(v.x); o.y = f2bf(v.y); o.z = f2bf(v.z); o.w = f2bf(v.w);
  *(ushort4*)(dst + (size_t)r * ostride + ooff + cc) = o;
}

// qkb[n] += partial of bq @ Wk (qkb pre-zeroed via memset)
__global__ __launch_bounds__(256) void bqwk_k(
    const float* __restrict__ bq, const float* __restrict__ Wk,
    float* __restrict__ qkb)
{
  int n = blockIdx.x * 256 + threadIdx.x;
  int j0 = blockIdx.y * 64;
  float s = 0.f;
#pragma unroll 8
  for (int j = j0; j < j0 + 64; ++j) s += bq[j] * Wk[(size_t)j * 1024 + n];
  atomicAdd(&qkb[n], s);
}

// ---------------- fused LSTM elementwise + attention finish (partials) ------
__global__ __launch_bounds__(256) void lstmfin_k(
    const u16* __restrict__ gparts, const float* __restrict__ c,
    const float* __restrict__ b_ih, const float* __restrict__ b_hh,
    const float* __restrict__ Qk, const float* __restrict__ attst,
    float* __restrict__ out_h, float* __restrict__ out_c,
    u16* __restrict__ ctxb)
{
  const int b = blockIdx.x;
  const int t = threadIdx.x;
  const int lane = t & 63, wv_id = t >> 6;
  const int p = t * 4;
  const u16* g0 = gparts + (size_t)b * 4096;
  const u16* g1 = g0 + (size_t)2048 * 4096;
  float4 cv = *(const float4*)(c + (size_t)b * 1024 + p);
  float cvs[4] = {cv.x, cv.y, cv.z, cv.w};

  float hn[4], cn[4];
  float gsum[4][4];
#pragma unroll
  for (int gi = 0; gi < 4; ++gi) {
    ushort4 a = *(const ushort4*)(g0 + gi * 1024 + p);
    ushort4 bb = *(const ushort4*)(g1 + gi * 1024 + p);
    float4 bi = *(const float4*)(b_ih + gi * 1024 + p);
    float4 bh = *(const float4*)(b_hh + gi * 1024 + p);
    gsum[gi][0] = bf2f(a.x) + bf2f(bb.x) + bi.x + bh.x;
    gsum[gi][1] = bf2f(a.y) + bf2f(bb.y) + bi.y + bh.y;
    gsum[gi][2] = bf2f(a.z) + bf2f(bb.z) + bi.z + bh.z;
    gsum[gi][3] = bf2f(a.w) + bf2f(bb.w) + bi.w + bh.w;
  }
#pragma unroll
  for (int j = 0; j < 4; ++j) {
    float si = 1.f / (1.f + __expf(-gsum[0][j]));
    float sf = 1.f / (1.f + __expf(-gsum[1][j]));
    float so = 1.f / (1.f + __expf(-gsum[3][j]));
    float tg = 2.f / (1.f + __expf(-2.f * gsum[2][j])) - 1.f;
    cn[j] = sf * cvs[j] + si * tg;
    float tc2 = 2.f / (1.f + __expf(-2.f * cn[j])) - 1.f;
    hn[j] = so * tc2;
  }
  *(float4*)(out_c + (size_t)b * 1024 + p) = make_float4(cn[0], cn[1], cn[2], cn[3]);
  *(float4*)(out_h + (size_t)b * 1024 + p) = make_float4(hn[0], hn[1], hn[2], hn[3]);

  float4 qv = *(const float4*)(Qk + (size_t)b * 1024 + p);
  float part = qv.x * hn[0] + qv.y * hn[1] + qv.z * hn[2] + qv.w * hn[3];
#pragma unroll
  for (int off = 32; off; off >>= 1) part += __shfl_xor(part, off);
  __shared__ float red[4];
  if (lane == 0) red[wv_id] = part;
  __syncthreads();
  float s_last = (red[0] + red[1] + red[2] + red[3]) * 0.03125f;

  const float* st = attst + (size_t)b * 1032;
  float m_run = st[1024], l = st[1025];
  float4 cx = *(const float4*)(st + p);
  if (s_last <= m_run + 8.f) {
    float e = __expf(s_last - m_run);
    l += e;
    cx.x += e * hn[0]; cx.y += e * hn[1]; cx.z += e * hn[2]; cx.w += e * hn[3];
  } else {
    float sc = __expf(m_run - s_last);
    l = l * sc + 1.f;
    cx.x = cx.x * sc + hn[0]; cx.y = cx.y * sc + hn[1];
    cx.z = cx.z * sc + hn[2]; cx.w = cx.w * sc + hn[3];
  }
  float inv = 1.f / l;
  ushort4 o;
  o.x = f2bf(cx.x * inv); o.y = f2bf(cx.y * inv);
  o.z = f2bf(cx.z * inv); o.w = f2bf(cx.w * inv);
  *(ushort4*)(ctxb + (size_t)b * 1024 + p) = o;
}

extern "C" void kernel_launch(void* const* d_in, const int* in_sizes, int n_in,
                              void* d_out, int out_size, void* d_ws, size_t ws_size,
                              hipStream_t stream) {
  const int Bb = 2048, Hh = 1024;
  const float* pose  = (const float*)d_in[0];
  const float* query = (const float*)d_in[1];
  const float* h     = (const float*)d_in[2];
  const float* c     = (const float*)d_in[3];
  const float* mem   = (const float*)d_in[4];
  const float* W_ih  = (const float*)d_in[5];
  const float* W_hh  = (const float*)d_in[6];
  const float* b_ih  = (const float*)d_in[7];
  const float* b_hh  = (const float*)d_in[8];
  const float* Wq    = (const float*)d_in[9];
  const float* bq    = (const float*)d_in[10];
  const float* Wk    = (const float*)d_in[11];
  // d_in[12] = bk: m-independent score shift, cancels in softmax
  const float* Wv    = (const float*)d_in[13];
  const float* bv    = (const float*)d_in[14];

  float* out_att = (float*)d_out;
  float* out_h   = out_att + (size_t)Bb * Hh;
  float* out_c   = out_h + (size_t)Bb * Hh;

  char* wp = (char*)d_ws;
  auto alloc = [&](size_t bytes) {
    char* p = wp; wp += (bytes + 255) & ~(size_t)255; return p;
  };
  u16*   Xcat  = (u16*)alloc((size_t)2048 * 2048 * 2);   // 8 MB
  u16*   Wcat  = (u16*)alloc((size_t)4096 * 2048 * 2);   // 16 MB
  // next 4 contiguous, all dead before attn -> attst aliases them
  u16*   Qryb  = (u16*)alloc((size_t)2048 * 1024 * 2);   // 4 MB
  u16*   WqTb  = (u16*)alloc((size_t)1024 * 1024 * 2);   // 2 MB
  u16*   WkTb  = (u16*)alloc((size_t)1024 * 1024 * 2);   // 2 MB
  u16*   Gb    = (u16*)alloc((size_t)1024 * 1024 * 2);   // 2 MB
  u16*   Wvb   = (u16*)alloc((size_t)1024 * 1024 * 2);   // 2 MB (live through final)
  u16*   gparts= (u16*)alloc((size_t)2 * 2048 * 4096 * 2); // 32 MB (bf16 x2 halves)
  float* qkb   = (float*)alloc((size_t)1024 * 4);
  float* Qk    = (float*)alloc((size_t)2048 * 1024 * 4); // 8 MB
  u16*   ctxb  = (u16*)alloc((size_t)2048 * 1024 * 2);   // 4 MB
  float* attst = (float*)Qryb;   // [2048][1032] f32 = 8.45 MB < 10 MB alias pool

  // 1. all conversions in one kernel
  prep_k<<<15872, 256, 0, stream>>>(pose, h, W_ih, W_hh, query, Wv, Wq, Wk,
                                    Xcat, Wcat, Qryb, Wvb, WqTb, WkTb);

  // 2. qkb = bq @ Wk (tiny)
  hipMemsetAsync(qkb, 0, 1024 * sizeof(float), stream);
  bqwk_k<<<dim3(4, 16), 256, 0, stream>>>(bq, Wk, qkb);

  // 3. G[n,j] = sum_a Wk[a,n]*Wq[a,j]  (query @ G^T == (query@Wq^T)@Wk)
  gemm_bt<<<dim3(8, 8), 256, 0, stream>>>(
      WkTb, WqTb, nullptr, Gb, nullptr, 1024, 1024, 1024);

  // 4. Qk = query @ G^T + bq@Wk
  gemm_bt<<<dim3(8, 16), 256, 0, stream>>>(
      Qryb, Gb, Qk, nullptr, qkb, 2048, 1024, 1024);

  // 5. gates: 256^2 8-wave counted-vmcnt kernel, K-split x2 -> bf16 partials
  gates8_k<<<256, 512, 0, stream>>>(Xcat, Wcat, gparts);

  // 6. attention partial solo (full-GPU streaming: 2048 waves)
  attn_k<<<512, 256, 0, stream>>>(Qk, mem, attst);

  // 7. LSTM elementwise (sum partials + biases) + attention finish -> ctx
  lstmfin_k<<<2048, 256, 0, stream>>>(gparts, c, b_ih, b_hh, Qk, attst,
                                      out_h, out_c, ctxb);

  // 8. attended = ctx @ Wv^T + bv
  gemm_bt<<<dim3(8, 16), 256, 0, stream>>>(
      ctxb, Wvb, out_att, nullptr, bv, 2048, 1024, 1024);
}

// Round 13
// 241.081 us; speedup vs baseline: 1.1080x; 1.0304x over previous
//
#include <hip/hip_runtime.h>
#include <stdint.h>

typedef __attribute__((ext_vector_type(8))) short short8;
typedef __attribute__((ext_vector_type(4))) float f32x4;
typedef unsigned short u16;

#define SBAR() do { __builtin_amdgcn_sched_barrier(0); \
                    __builtin_amdgcn_s_barrier(); \
                    __builtin_amdgcn_sched_barrier(0); } while (0)

__device__ __forceinline__ u16 f2bf(float f) {
  union { float f; uint32_t u; } v; v.f = f;
  return (u16)((v.u + 0x7FFFu + ((v.u >> 16) & 1u)) >> 16);
}
__device__ __forceinline__ float bf2f(u16 u) {
  union { uint32_t u; float f; } v; v.u = (uint32_t)u << 16; return v.f;
}

__device__ __forceinline__ void gl_lds16(const void* g, void* l) {
  __builtin_amdgcn_global_load_lds(
      (const __attribute__((address_space(1))) void*)g,
      (__attribute__((address_space(3))) void*)l, 16, 0, 0);
}

// ---------------- generic GEMM (plain m97 structure, 128x128) ----------------
__global__ __launch_bounds__(256) void gemm_bt(
    const u16* __restrict__ A, const u16* __restrict__ B,
    float* __restrict__ Cf, u16* __restrict__ Cb,
    const float* __restrict__ bias1,
    int M, int N, int K)
{
  __shared__ __align__(16) u16 As[128 * 32];
  __shared__ __align__(16) u16 Bs[128 * 32];
  const int t = threadIdx.x;
  const int lane = t & 63;
  const int w = t >> 6;
  const int wr = w >> 1, wc = w & 1;
  const int m0 = blockIdx.y * 128, n0 = blockIdx.x * 128;
  const int lr = lane & 15;
  const int lk = (lane >> 4) * 8;
  const int srow = t >> 2;
  const int scol = (t & 3) * 8;

  const u16* gA = A + (size_t)(m0 + srow) * K + scol;
  const u16* gB = B + (size_t)(n0 + srow) * K + scol;

  f32x4 acc[4][4] = {};

  for (int k0 = 0; k0 < K; k0 += 32) {
    gl_lds16(gA,                  As + t * 8);
    gl_lds16(gA + (size_t)64 * K, As + 2048 + t * 8);
    gl_lds16(gB,                  Bs + t * 8);
    gl_lds16(gB + (size_t)64 * K, Bs + 2048 + t * 8);
    gA += 32; gB += 32;
    __syncthreads();

    short8 a[4], b[4];
#pragma unroll
    for (int m = 0; m < 4; ++m)
      a[m] = *(const short8*)(As + (wr * 64 + m * 16 + lr) * 32 + lk);
#pragma unroll
    for (int n = 0; n < 4; ++n)
      b[n] = *(const short8*)(Bs + (wc * 64 + n * 16 + lr) * 32 + lk);
#pragma unroll
    for (int m = 0; m < 4; ++m)
#pragma unroll
      for (int n = 0; n < 4; ++n)
        acc[m][n] = __builtin_amdgcn_mfma_f32_16x16x32_bf16(a[m], b[n], acc[m][n], 0, 0, 0);
    __syncthreads();
  }

#pragma unroll
  for (int n = 0; n < 4; ++n) {
    int col = n0 + wc * 64 + n * 16 + lr;
    float bsum = bias1 ? bias1[col] : 0.f;
#pragma unroll
    for (int m = 0; m < 4; ++m) {
#pragma unroll
      for (int r = 0; r < 4; ++r) {
        int row = m0 + wr * 64 + m * 16 + (lane >> 4) * 4 + r;
        float vv = acc[m][n][r] + bsum;
        if (Cf) Cf[(size_t)row * N + col] = vv;
        if (Cb) Cb[(size_t)row * N + col] = f2bf(vv);
      }
    }
  }
}

// ---------------- gates GEMM: 256x256, BK=64, 8-wave, counted-vmcnt ----------
// (verbatim R12) K-split x2 -> 256 blocks x 512 threads, 128KB LDS, 1 blk/CU.
__global__ __launch_bounds__(512) void gates8_k(
    const u16* __restrict__ Xcat, const u16* __restrict__ Wcat,
    u16* __restrict__ gparts)
{
  __shared__ __align__(16) u16 lds[65536];     // 128 KB
  const int t = threadIdx.x;
  const int l = t & 63;
  const int w = t >> 6;
  const int wr = w >> 2, wc = w & 3;
  const int bid = blockIdx.x;
  const int tile = bid >> 1, khalf = bid & 1;
  const int m0 = (tile >> 4) * 256;
  const int n0 = (tile & 15) * 256;
  const int lr = l & 15;
  const int l4 = l >> 4;

  const int sr = l >> 3;
  const int sc = ((l & 7) * 8) ^ ((l >> 5) << 4);

  const u16* Abase = Xcat + (size_t)m0 * 2048 + khalf * 1024 + sc;
  const u16* Bbase = Wcat + (size_t)n0 * 2048 + khalf * 1024 + sc;

  #define STAGE(buf, kt) do {                                                  \
    const int kof_ = (kt) * 64;                                                \
    _Pragma("unroll")                                                          \
    for (int hh = 0; hh < 2; ++hh)                                             \
      _Pragma("unroll")                                                        \
      for (int j = 0; j < 2; ++j) {                                            \
        int row_ = hh * 128 + (w + 8 * j) * 8 + sr;                            \
        char* dA = (char*)lds + (buf) * 65536 + hh * 16384 + (w + 8*j) * 1024 + l * 16; \
        char* dB = dA + 32768;                                                 \
        gl_lds16(Abase + (size_t)row_ * 2048 + kof_, dA);                      \
        gl_lds16(Bbase + (size_t)row_ * 2048 + kof_, dB);                      \
      }                                                                        \
  } while (0)

  auto LDA = [&](int buf, int mf, int s) -> short8 {
    int rr = mf * 16 + lr;
    int cb = (s * 64 + l4 * 16) ^ (((rr >> 2) & 1) << 5);
    return *(const short8*)((const char*)lds + buf * 65536 + wr * 16384 + rr * 128 + cb);
  };
  auto LDB = [&](int buf, int nf, int s) -> short8 {
    int rr = (wc & 1) * 64 + nf * 16 + lr;
    int cb = (s * 64 + l4 * 16) ^ (((rr >> 2) & 1) << 5);
    return *(const short8*)((const char*)lds + buf * 65536 + 32768 + (wc >> 1) * 16384 + rr * 128 + cb);
  };

  f32x4 acc[8][4] = {};

  STAGE(0, 0);
  STAGE(1, 1);
  asm volatile("s_waitcnt vmcnt(8)" ::: "memory");
  SBAR();

  for (int kt = 0; kt < 16; ++kt) {
    const int cur = kt & 1;
    short8 a0[4][2], a1[4][2], b[2][2];
#pragma unroll
    for (int i = 0; i < 4; ++i) { a0[i][0] = LDA(cur, i, 0); a0[i][1] = LDA(cur, i, 1); }
#pragma unroll
    for (int n = 0; n < 2; ++n) { b[n][0] = LDB(cur, n, 0); b[n][1] = LDB(cur, n, 1); }
    __builtin_amdgcn_s_setprio(1);
#pragma unroll
    for (int i = 0; i < 4; ++i)
#pragma unroll
      for (int n = 0; n < 2; ++n)
#pragma unroll
        for (int s = 0; s < 2; ++s)
          acc[i][n] = __builtin_amdgcn_mfma_f32_16x16x32_bf16(a0[i][s], b[n][s], acc[i][n], 0, 0, 0);
    __builtin_amdgcn_s_setprio(0);
#pragma unroll
    for (int i = 0; i < 4; ++i) { a1[i][0] = LDA(cur, 4 + i, 0); a1[i][1] = LDA(cur, 4 + i, 1); }
    __builtin_amdgcn_s_setprio(1);
#pragma unroll
    for (int i = 0; i < 4; ++i)
#pragma unroll
      for (int n = 0; n < 2; ++n)
#pragma unroll
        for (int s = 0; s < 2; ++s)
          acc[4 + i][n] = __builtin_amdgcn_mfma_f32_16x16x32_bf16(a1[i][s], b[n][s], acc[4 + i][n], 0, 0, 0);
    __builtin_amdgcn_s_setprio(0);
#pragma unroll
    for (int n = 0; n < 2; ++n) { b[n][0] = LDB(cur, 2 + n, 0); b[n][1] = LDB(cur, 2 + n, 1); }
    __builtin_amdgcn_s_setprio(1);
#pragma unroll
    for (int i = 0; i < 4; ++i)
#pragma unroll
      for (int n = 0; n < 2; ++n)
#pragma unroll
        for (int s = 0; s < 2; ++s)
          acc[4 + i][2 + n] = __builtin_amdgcn_mfma_f32_16x16x32_bf16(a1[i][s], b[n][s], acc[4 + i][2 + n], 0, 0, 0);
#pragma unroll
    for (int i = 0; i < 4; ++i)
#pragma unroll
      for (int n = 0; n < 2; ++n)
#pragma unroll
        for (int s = 0; s < 2; ++s)
          acc[i][2 + n] = __builtin_amdgcn_mfma_f32_16x16x32_bf16(a0[i][s], b[n][s], acc[i][2 + n], 0, 0, 0);
    __builtin_amdgcn_s_setprio(0);

    SBAR();
    if (kt + 2 < 16) {
      STAGE(cur, kt + 2);
      asm volatile("s_waitcnt vmcnt(8)" ::: "memory");
    } else {
      asm volatile("s_waitcnt vmcnt(0)" ::: "memory");
    }
    SBAR();
  }
  #undef STAGE

  u16* out = gparts + (size_t)khalf * 2048 * 4096;
#pragma unroll
  for (int nf = 0; nf < 4; ++nf) {
    int col = n0 + wc * 64 + nf * 16 + lr;
#pragma unroll
    for (int mf = 0; mf < 8; ++mf)
#pragma unroll
      for (int r = 0; r < 4; ++r) {
        int row = m0 + wr * 128 + mf * 16 + l4 * 4 + r;
        out[(size_t)row * 4096 + col] = f2bf(acc[mf][nf][r]);
      }
  }
}

// ---------------- prepQ: query pack + Wq/Wk transposes (runs first) ----------
__global__ __launch_bounds__(256) void prepQ_k(
    const float* __restrict__ query, const float* __restrict__ Wq,
    const float* __restrict__ Wk,
    u16* __restrict__ qry, u16* __restrict__ wqtb, u16* __restrict__ wktb)
{
  __shared__ u16 tile[64][65];
  int blk = blockIdx.x;
  int t = threadIdx.x;
  if (blk < 2048) {                       // query pack
    int cc = t * 4;
    float4 v = *(const float4*)(query + (size_t)blk * 1024 + cc);
    ushort4 o; o.x = f2bf(v.x); o.y = f2bf(v.y); o.z = f2bf(v.z); o.w = f2bf(v.w);
    *(ushort4*)(qry + (size_t)blk * 1024 + cc) = o;
    return;
  }
  const float* src; u16* dst; int tblk;
  if (blk < 2304) { src = Wq; dst = wqtb; tblk = blk - 2048; }
  else            { src = Wk; dst = wktb; tblk = blk - 2304; }
  int tr = (tblk >> 4) * 64, tc = (tblk & 15) * 64;
  int tx = t & 63;
  int ty = (t >> 6) * 16;
#pragma unroll
  for (int i = 0; i < 16; ++i)
    tile[ty + i][tx] = f2bf(src[(size_t)(tr + ty + i) * 1024 + tc + tx]);
  __syncthreads();
#pragma unroll
  for (int i = 0; i < 16; ++i)
    dst[(size_t)(tc + ty + i) * 1024 + tr + tx] = tile[tx][ty + i];
}

// ---------------- prepRG: G gemm + bqwk hidden under remaining packs --------
// blocks 0..63: G = WkTb @ WqTb^T (bf16, m97 tile). 64..67: qkb = bq@Wk.
// 68..13379: packs (pose, h, W_ih, W_hh, Wv).
__global__ __launch_bounds__(256) void prepRG_k(
    const float* __restrict__ pose, const float* __restrict__ h,
    const float* __restrict__ W_ih, const float* __restrict__ W_hh,
    const float* __restrict__ Wv,
    const u16* __restrict__ WkTb, const u16* __restrict__ WqTb,
    const float* __restrict__ bq, const float* __restrict__ Wk,
    u16* __restrict__ xcat, u16* __restrict__ wcat, u16* __restrict__ wvb,
    u16* __restrict__ Gb, float* __restrict__ qkb)
{
  __shared__ __align__(16) u16 As[128 * 32];
  __shared__ __align__(16) u16 Bs[128 * 32];
  const int blk = blockIdx.x;
  const int t = threadIdx.x;
  if (blk < 64) {
    // ---- G tile (m97): C[row,col] = sum_j WkTb[row,j]*WqTb[col,j], 1024^3 ----
    const int lane = t & 63;
    const int w = t >> 6;
    const int wr = w >> 1, wc = w & 1;
    const int m0 = (blk >> 3) * 128, n0 = (blk & 7) * 128;
    const int lr = lane & 15;
    const int lk = (lane >> 4) * 8;
    const int srow = t >> 2;
    const int scol = (t & 3) * 8;
    const u16* gA = WkTb + (size_t)(m0 + srow) * 1024 + scol;
    const u16* gB = WqTb + (size_t)(n0 + srow) * 1024 + scol;
    f32x4 acc[4][4] = {};
    for (int k0 = 0; k0 < 1024; k0 += 32) {
      gl_lds16(gA,                     As + t * 8);
      gl_lds16(gA + (size_t)64 * 1024, As + 2048 + t * 8);
      gl_lds16(gB,                     Bs + t * 8);
      gl_lds16(gB + (size_t)64 * 1024, Bs + 2048 + t * 8);
      gA += 32; gB += 32;
      __syncthreads();
      short8 a[4], b[4];
#pragma unroll
      for (int m = 0; m < 4; ++m)
        a[m] = *(const short8*)(As + (wr * 64 + m * 16 + lr) * 32 + lk);
#pragma unroll
      for (int n = 0; n < 4; ++n)
        b[n] = *(const short8*)(Bs + (wc * 64 + n * 16 + lr) * 32 + lk);
#pragma unroll
      for (int m = 0; m < 4; ++m)
#pragma unroll
        for (int n = 0; n < 4; ++n)
          acc[m][n] = __builtin_amdgcn_mfma_f32_16x16x32_bf16(a[m], b[n], acc[m][n], 0, 0, 0);
      __syncthreads();
    }
#pragma unroll
    for (int n = 0; n < 4; ++n) {
      int col = n0 + wc * 64 + n * 16 + lr;
#pragma unroll
      for (int m = 0; m < 4; ++m)
#pragma unroll
        for (int r = 0; r < 4; ++r) {
          int row = m0 + wr * 64 + m * 16 + (lane >> 4) * 4 + r;
          Gb[(size_t)row * 1024 + col] = f2bf(acc[m][n][r]);
        }
    }
    return;
  }
  if (blk < 68) {
    // ---- qkb[n] = sum_j bq[j] * Wk[j,n]  (no atomics, full column sums) ----
    int n = (blk - 64) * 256 + t;
    float s0 = 0.f, s1 = 0.f;
    for (int j = 0; j < 1024; j += 2) {
      s0 += bq[j]     * Wk[(size_t)j * 1024 + n];
      s1 += bq[j + 1] * Wk[(size_t)(j + 1) * 1024 + n];
    }
    qkb[n] = s0 + s1;
    return;
  }
  // ---- packs ----
  int b2 = blk - 68;
  const float* src; u16* dst; int ostride, ooff, base;
  if (b2 < 2048)       { src = pose;  dst = xcat; ostride = 2048; ooff = 0;    base = 0; }
  else if (b2 < 4096)  { src = h;     dst = xcat; ostride = 2048; ooff = 1024; base = 2048; }
  else if (b2 < 8192)  { src = W_ih;  dst = wcat; ostride = 2048; ooff = 0;    base = 4096; }
  else if (b2 < 12288) { src = W_hh;  dst = wcat; ostride = 2048; ooff = 1024; base = 8192; }
  else                 { src = Wv;    dst = wvb;  ostride = 1024; ooff = 0;    base = 12288; }
  int r = b2 - base;
  int cc = t * 4;
  float4 v = *(const float4*)(src + (size_t)r * 1024 + cc);
  ushort4 o; o.x = f2bf(v.x); o.y = f2bf(v.y); o.z = f2bf(v.z); o.w = f2bf(v.w);
  *(ushort4*)(dst + (size_t)r * ostride + ooff + cc) = o;
}

// ---------------- dedicated attention partial: rows 1..63, online softmax ----
__global__ __launch_bounds__(256) void attn_k(
    const float* __restrict__ Qk, const float* __restrict__ mem,
    float* __restrict__ attst)
{
  const int t = threadIdx.x;
  const int lane = t & 63;
  const int b = blockIdx.x * 4 + (t >> 6);
  const float* q = Qk + (size_t)b * 1024;
  f32x4 qv[4];
#pragma unroll
  for (int i = 0; i < 4; ++i)
    qv[i] = *(const f32x4*)(q + (i * 64 + lane) * 4);
  const float* mb = mem + (size_t)b * 65536;

  float m_run = -3e38f, l = 0.f;
  f32x4 cx[4] = {};

  for (int qd = 0; qd < 15; ++qd) {
    const float* r0 = mb + (size_t)(1 + qd * 4) * 1024;
    f32x4 rv[4][4];
    float s[4] = {0.f, 0.f, 0.f, 0.f};
#pragma unroll
    for (int rr = 0; rr < 4; ++rr)
#pragma unroll
      for (int i = 0; i < 4; ++i) {
        rv[rr][i] = __builtin_nontemporal_load(
            (const f32x4*)(r0 + rr * 1024 + (i * 64 + lane) * 4));
        s[rr] += rv[rr][i][0] * qv[i][0] + rv[rr][i][1] * qv[i][1] +
                 rv[rr][i][2] * qv[i][2] + rv[rr][i][3] * qv[i][3];
      }
#pragma unroll
    for (int rr = 0; rr < 4; ++rr) {
#pragma unroll
      for (int off = 32; off; off >>= 1) s[rr] += __shfl_xor(s[rr], off);
      s[rr] *= 0.03125f;
    }
#pragma unroll
    for (int rr = 0; rr < 4; ++rr) {
      if (s[rr] <= m_run + 8.f) {
        float e = __expf(s[rr] - m_run);
        l += e;
#pragma unroll
        for (int i = 0; i < 4; ++i) cx[i] += rv[rr][i] * e;
      } else {
        float sc = __expf(m_run - s[rr]);
        m_run = s[rr];
        l = l * sc + 1.f;
#pragma unroll
        for (int i = 0; i < 4; ++i) cx[i] = cx[i] * sc + rv[rr][i];
      }
    }
  }
  for (int r = 61; r <= 63; ++r) {
    const float* row = mb + (size_t)r * 1024;
    f32x4 rv[4];
    float s = 0.f;
#pragma unroll
    for (int i = 0; i < 4; ++i) {
      rv[i] = __builtin_nontemporal_load(
          (const f32x4*)(row + (i * 64 + lane) * 4));
      s += rv[i][0] * qv[i][0] + rv[i][1] * qv[i][1] +
           rv[i][2] * qv[i][2] + rv[i][3] * qv[i][3];
    }
#pragma unroll
    for (int off = 32; off; off >>= 1) s += __shfl_xor(s, off);
    s *= 0.03125f;
    if (s <= m_run + 8.f) {
      float e = __expf(s - m_run);
      l += e;
#pragma unroll
      for (int i = 0; i < 4; ++i) cx[i] += rv[i] * e;
    } else {
      float sc = __expf(m_run - s);
      m_run = s;
      l = l * sc + 1.f;
#pragma unroll
      for (int i = 0; i < 4; ++i) cx[i] = cx[i] * sc + rv[i];
    }
  }
  float* st = attst + (size_t)b * 1032;
#pragma unroll
  for (int i = 0; i < 4; ++i)
    *(f32x4*)(st + (i * 64 + lane) * 4) = cx[i];
  if (lane == 0) { st[1024] = m_run; st[1025] = l; }
}

// ---------------- fused LSTM elementwise + attention finish (partials) ------
__global__ __launch_bounds__(256) void lstmfin_k(
    const u16* __restrict__ gparts, const float* __restrict__ c,
    const float* __restrict__ b_ih, const float* __restrict__ b_hh,
    const float* __restrict__ Qk, const float* __restrict__ attst,
    float* __restrict__ out_h, float* __restrict__ out_c,
    u16* __restrict__ ctxb)
{
  const int b = blockIdx.x;
  const int t = threadIdx.x;
  const int lane = t & 63, wv_id = t >> 6;
  const int p = t * 4;
  const u16* g0 = gparts + (size_t)b * 4096;
  const u16* g1 = g0 + (size_t)2048 * 4096;
  float4 cv = *(const float4*)(c + (size_t)b * 1024 + p);
  float cvs[4] = {cv.x, cv.y, cv.z, cv.w};

  float hn[4], cn[4];
  float gsum[4][4];
#pragma unroll
  for (int gi = 0; gi < 4; ++gi) {
    ushort4 a = *(const ushort4*)(g0 + gi * 1024 + p);
    ushort4 bb = *(const ushort4*)(g1 + gi * 1024 + p);
    float4 bi = *(const float4*)(b_ih + gi * 1024 + p);
    float4 bh = *(const float4*)(b_hh + gi * 1024 + p);
    gsum[gi][0] = bf2f(a.x) + bf2f(bb.x) + bi.x + bh.x;
    gsum[gi][1] = bf2f(a.y) + bf2f(bb.y) + bi.y + bh.y;
    gsum[gi][2] = bf2f(a.z) + bf2f(bb.z) + bi.z + bh.z;
    gsum[gi][3] = bf2f(a.w) + bf2f(bb.w) + bi.w + bh.w;
  }
#pragma unroll
  for (int j = 0; j < 4; ++j) {
    float si = 1.f / (1.f + __expf(-gsum[0][j]));
    float sf = 1.f / (1.f + __expf(-gsum[1][j]));
    float so = 1.f / (1.f + __expf(-gsum[3][j]));
    float tg = 2.f / (1.f + __expf(-2.f * gsum[2][j])) - 1.f;
    cn[j] = sf * cvs[j] + si * tg;
    float tc2 = 2.f / (1.f + __expf(-2.f * cn[j])) - 1.f;
    hn[j] = so * tc2;
  }
  *(float4*)(out_c + (size_t)b * 1024 + p) = make_float4(cn[0], cn[1], cn[2], cn[3]);
  *(float4*)(out_h + (size_t)b * 1024 + p) = make_float4(hn[0], hn[1], hn[2], hn[3]);

  float4 qv = *(const float4*)(Qk + (size_t)b * 1024 + p);
  float part = qv.x * hn[0] + qv.y * hn[1] + qv.z * hn[2] + qv.w * hn[3];
#pragma unroll
  for (int off = 32; off; off >>= 1) part += __shfl_xor(part, off);
  __shared__ float red[4];
  if (lane == 0) red[wv_id] = part;
  __syncthreads();
  float s_last = (red[0] + red[1] + red[2] + red[3]) * 0.03125f;

  const float* st = attst + (size_t)b * 1032;
  float m_run = st[1024], l = st[1025];
  float4 cx = *(const float4*)(st + p);
  if (s_last <= m_run + 8.f) {
    float e = __expf(s_last - m_run);
    l += e;
    cx.x += e * hn[0]; cx.y += e * hn[1]; cx.z += e * hn[2]; cx.w += e * hn[3];
  } else {
    float sc = __expf(m_run - s_last);
    l = l * sc + 1.f;
    cx.x = cx.x * sc + hn[0]; cx.y = cx.y * sc + hn[1];
    cx.z = cx.z * sc + hn[2]; cx.w = cx.w * sc + hn[3];
  }
  float inv = 1.f / l;
  ushort4 o;
  o.x = f2bf(cx.x * inv); o.y = f2bf(cx.y * inv);
  o.z = f2bf(cx.z * inv); o.w = f2bf(cx.w * inv);
  *(ushort4*)(ctxb + (size_t)b * 1024 + p) = o;
}

extern "C" void kernel_launch(void* const* d_in, const int* in_sizes, int n_in,
                              void* d_out, int out_size, void* d_ws, size_t ws_size,
                              hipStream_t stream) {
  const int Bb = 2048, Hh = 1024;
  const float* pose  = (const float*)d_in[0];
  const float* query = (const float*)d_in[1];
  const float* h     = (const float*)d_in[2];
  const float* c     = (const float*)d_in[3];
  const float* mem   = (const float*)d_in[4];
  const float* W_ih  = (const float*)d_in[5];
  const float* W_hh  = (const float*)d_in[6];
  const float* b_ih  = (const float*)d_in[7];
  const float* b_hh  = (const float*)d_in[8];
  const float* Wq    = (const float*)d_in[9];
  const float* bq    = (const float*)d_in[10];
  const float* Wk    = (const float*)d_in[11];
  // d_in[12] = bk: m-independent score shift, cancels in softmax
  const float* Wv    = (const float*)d_in[13];
  const float* bv    = (const float*)d_in[14];

  float* out_att = (float*)d_out;
  float* out_h   = out_att + (size_t)Bb * Hh;
  float* out_c   = out_h + (size_t)Bb * Hh;

  char* wp = (char*)d_ws;
  auto alloc = [&](size_t bytes) {
    char* p = wp; wp += (bytes + 255) & ~(size_t)255; return p;
  };
  u16*   Xcat  = (u16*)alloc((size_t)2048 * 2048 * 2);   // 8 MB
  u16*   Wcat  = (u16*)alloc((size_t)4096 * 2048 * 2);   // 16 MB
  // next 4 contiguous, all dead before attn -> attst aliases them
  u16*   Qryb  = (u16*)alloc((size_t)2048 * 1024 * 2);   // 4 MB
  u16*   WqTb  = (u16*)alloc((size_t)1024 * 1024 * 2);   // 2 MB
  u16*   WkTb  = (u16*)alloc((size_t)1024 * 1024 * 2);   // 2 MB
  u16*   Gb    = (u16*)alloc((size_t)1024 * 1024 * 2);   // 2 MB
  u16*   Wvb   = (u16*)alloc((size_t)1024 * 1024 * 2);   // 2 MB (live through final)
  u16*   gparts= (u16*)alloc((size_t)2 * 2048 * 4096 * 2); // 32 MB (bf16 x2 halves)
  float* qkb   = (float*)alloc((size_t)1024 * 4);
  float* Qk    = (float*)alloc((size_t)2048 * 1024 * 4); // 8 MB
  u16*   ctxb  = (u16*)alloc((size_t)2048 * 1024 * 2);   // 4 MB
  float* attst = (float*)Qryb;   // [2048][1032] f32 = 8.45 MB < 10 MB alias pool

  // 1. prepQ: query pack + Wq/Wk transposes (feeds G)
  prepQ_k<<<2560, 256, 0, stream>>>(query, Wq, Wk, Qryb, WqTb, WkTb);

  // 2. prepRG: G gemm (64 blk) + bqwk (4 blk) hidden under packs (13312 blk)
  prepRG_k<<<13380, 256, 0, stream>>>(pose, h, W_ih, W_hh, Wv,
                                      WkTb, WqTb, bq, Wk,
                                      Xcat, Wcat, Wvb, Gb, qkb);

  // 3. Qk = query @ G^T + bq@Wk
  gemm_bt<<<dim3(8, 16), 256, 0, stream>>>(
      Qryb, Gb, Qk, nullptr, qkb, 2048, 1024, 1024);

  // 4. gates: 256^2 8-wave counted-vmcnt kernel, K-split x2 -> bf16 partials
  gates8_k<<<256, 512, 0, stream>>>(Xcat, Wcat, gparts);

  // 5. attention partial solo (full-GPU streaming: 2048 waves)
  attn_k<<<512, 256, 0, stream>>>(Qk, mem, attst);

  // 6. LSTM elementwise (sum partials + biases) + attention finish -> ctx
  lstmfin_k<<<2048, 256, 0, stream>>>(gparts, c, b_ih, b_hh, Qk, attst,
                                      out_h, out_c, ctxb);

  // 7. attended = ctx @ Wv^T + bv
  gemm_bt<<<dim3(8, 16), 256, 0, stream>>>(
      ctxb, Wvb, out_att, nullptr, bv, 2048, 1024, 1024);
}

// Round 14
// 238.389 us; speedup vs baseline: 1.1205x; 1.0113x over previous
//
#include <hip/hip_runtime.h>
#include <stdint.h>

typedef __attribute__((ext_vector_type(8))) short short8;
typedef __attribute__((ext_vector_type(4))) float f32x4;
typedef unsigned short u16;

#define SBAR() do { __builtin_amdgcn_sched_barrier(0); \
                    __builtin_amdgcn_s_barrier(); \
                    __builtin_amdgcn_sched_barrier(0); } while (0)

__device__ __forceinline__ u16 f2bf(float f) {
  union { float f; uint32_t u; } v; v.f = f;
  return (u16)((v.u + 0x7FFFu + ((v.u >> 16) & 1u)) >> 16);
}
__device__ __forceinline__ float bf2f(u16 u) {
  union { uint32_t u; float f; } v; v.u = (uint32_t)u << 16; return v.f;
}

__device__ __forceinline__ void gl_lds16(const void* g, void* l) {
  __builtin_amdgcn_global_load_lds(
      (const __attribute__((address_space(1))) void*)g,
      (__attribute__((address_space(3))) void*)l, 16, 0, 0);
}

// ---------------- generic GEMM (plain m97 structure, 128x128) ----------------
__global__ __launch_bounds__(256) void gemm_bt(
    const u16* __restrict__ A, const u16* __restrict__ B,
    float* __restrict__ Cf, u16* __restrict__ Cb,
    const float* __restrict__ bias1,
    int M, int N, int K)
{
  __shared__ __align__(16) u16 As[128 * 32];
  __shared__ __align__(16) u16 Bs[128 * 32];
  const int t = threadIdx.x;
  const int lane = t & 63;
  const int w = t >> 6;
  const int wr = w >> 1, wc = w & 1;
  const int m0 = blockIdx.y * 128, n0 = blockIdx.x * 128;
  const int lr = lane & 15;
  const int lk = (lane >> 4) * 8;
  const int srow = t >> 2;
  const int scol = (t & 3) * 8;

  const u16* gA = A + (size_t)(m0 + srow) * K + scol;
  const u16* gB = B + (size_t)(n0 + srow) * K + scol;

  f32x4 acc[4][4] = {};

  for (int k0 = 0; k0 < K; k0 += 32) {
    gl_lds16(gA,                  As + t * 8);
    gl_lds16(gA + (size_t)64 * K, As + 2048 + t * 8);
    gl_lds16(gB,                  Bs + t * 8);
    gl_lds16(gB + (size_t)64 * K, Bs + 2048 + t * 8);
    gA += 32; gB += 32;
    __syncthreads();

    short8 a[4], b[4];
#pragma unroll
    for (int m = 0; m < 4; ++m)
      a[m] = *(const short8*)(As + (wr * 64 + m * 16 + lr) * 32 + lk);
#pragma unroll
    for (int n = 0; n < 4; ++n)
      b[n] = *(const short8*)(Bs + (wc * 64 + n * 16 + lr) * 32 + lk);
#pragma unroll
    for (int m = 0; m < 4; ++m)
#pragma unroll
      for (int n = 0; n < 4; ++n)
        acc[m][n] = __builtin_amdgcn_mfma_f32_16x16x32_bf16(a[m], b[n], acc[m][n], 0, 0, 0);
    __syncthreads();
  }

#pragma unroll
  for (int n = 0; n < 4; ++n) {
    int col = n0 + wc * 64 + n * 16 + lr;
    float bsum = bias1 ? bias1[col] : 0.f;
#pragma unroll
    for (int m = 0; m < 4; ++m) {
#pragma unroll
      for (int r = 0; r < 4; ++r) {
        int row = m0 + wr * 64 + m * 16 + (lane >> 4) * 4 + r;
        float vv = acc[m][n][r] + bsum;
        if (Cf) Cf[(size_t)row * N + col] = vv;
        if (Cb) Cb[(size_t)row * N + col] = f2bf(vv);
      }
    }
  }
}

// ---------------- gates GEMM: 256x256, BK=64, 8-wave, counted-vmcnt ----------
// K-split x2 -> 256 blocks x 512 threads, 128KB LDS, 1 blk/CU.
// NEW (R14): 3-bit row-swizzle swz(row) = ((row>>1)&7)<<4 bytes, applied on
// BOTH the pre-swizzled global staging source and the ds_read address.
// Spreads each wave's ds_read_b128 over all 32 banks (2 lanes/bank = free).
__global__ __launch_bounds__(512) void gates8_k(
    const u16* __restrict__ Xcat, const u16* __restrict__ Wcat,
    u16* __restrict__ gparts)
{
  __shared__ __align__(16) u16 lds[65536];     // 128 KB
  const int t = threadIdx.x;
  const int l = t & 63;
  const int w = t >> 6;
  const int wr = w >> 2, wc = w & 3;
  const int bid = blockIdx.x;
  const int tile = bid >> 1, khalf = bid & 1;
  const int m0 = (tile >> 4) * 256;
  const int n0 = (tile & 15) * 256;
  const int lr = l & 15;
  const int l4 = l >> 4;

  // staging: LDS row for lane l = (w+8j)*8 + (l>>3) (+hh*128); its bits 1..3
  // are ((l>>4)&3) | ((w&1)<<2) -> pre-swizzle the global column accordingly.
  const int sr = l >> 3;
  const int sc = ((l & 7) * 8) ^ (((((l >> 4) & 3) | ((w & 1) << 2))) << 3); // elems

  const u16* Abase = Xcat + (size_t)m0 * 2048 + khalf * 1024 + sc;
  const u16* Bbase = Wcat + (size_t)n0 * 2048 + khalf * 1024 + sc;

  #define STAGE(buf, kt) do {                                                  \
    const int kof_ = (kt) * 64;                                                \
    _Pragma("unroll")                                                          \
    for (int hh = 0; hh < 2; ++hh)                                             \
      _Pragma("unroll")                                                        \
      for (int j = 0; j < 2; ++j) {                                            \
        int row_ = hh * 128 + (w + 8 * j) * 8 + sr;                            \
        char* dA = (char*)lds + (buf) * 65536 + hh * 16384 + (w + 8*j) * 1024 + l * 16; \
        char* dB = dA + 32768;                                                 \
        gl_lds16(Abase + (size_t)row_ * 2048 + kof_, dA);                      \
        gl_lds16(Bbase + (size_t)row_ * 2048 + kof_, dB);                      \
      }                                                                        \
  } while (0)

  // frag reads: rr bits 1..3 == (lr>>1)&7 for every frag base (multiples of 16/64)
  auto LDA = [&](int buf, int mf, int s) -> short8 {
    int rr = mf * 16 + lr;
    int cb = (s * 64 + l4 * 16) ^ (((lr >> 1) & 7) << 4);   // bytes
    return *(const short8*)((const char*)lds + buf * 65536 + wr * 16384 + rr * 128 + cb);
  };
  auto LDB = [&](int buf, int nf, int s) -> short8 {
    int rr = (wc & 1) * 64 + nf * 16 + lr;
    int cb = (s * 64 + l4 * 16) ^ (((lr >> 1) & 7) << 4);   // bytes
    return *(const short8*)((const char*)lds + buf * 65536 + 32768 + (wc >> 1) * 16384 + rr * 128 + cb);
  };

  f32x4 acc[8][4] = {};

  STAGE(0, 0);
  STAGE(1, 1);
  asm volatile("s_waitcnt vmcnt(8)" ::: "memory");
  SBAR();

  for (int kt = 0; kt < 16; ++kt) {
    const int cur = kt & 1;
    short8 a0[4][2], a1[4][2], b[2][2];
#pragma unroll
    for (int i = 0; i < 4; ++i) { a0[i][0] = LDA(cur, i, 0); a0[i][1] = LDA(cur, i, 1); }
#pragma unroll
    for (int n = 0; n < 2; ++n) { b[n][0] = LDB(cur, n, 0); b[n][1] = LDB(cur, n, 1); }
    __builtin_amdgcn_s_setprio(1);
#pragma unroll
    for (int i = 0; i < 4; ++i)
#pragma unroll
      for (int n = 0; n < 2; ++n)
#pragma unroll
        for (int s = 0; s < 2; ++s)
          acc[i][n] = __builtin_amdgcn_mfma_f32_16x16x32_bf16(a0[i][s], b[n][s], acc[i][n], 0, 0, 0);
    __builtin_amdgcn_s_setprio(0);
#pragma unroll
    for (int i = 0; i < 4; ++i) { a1[i][0] = LDA(cur, 4 + i, 0); a1[i][1] = LDA(cur, 4 + i, 1); }
    __builtin_amdgcn_s_setprio(1);
#pragma unroll
    for (int i = 0; i < 4; ++i)
#pragma unroll
      for (int n = 0; n < 2; ++n)
#pragma unroll
        for (int s = 0; s < 2; ++s)
          acc[4 + i][n] = __builtin_amdgcn_mfma_f32_16x16x32_bf16(a1[i][s], b[n][s], acc[4 + i][n], 0, 0, 0);
    __builtin_amdgcn_s_setprio(0);
#pragma unroll
    for (int n = 0; n < 2; ++n) { b[n][0] = LDB(cur, 2 + n, 0); b[n][1] = LDB(cur, 2 + n, 1); }
    __builtin_amdgcn_s_setprio(1);
#pragma unroll
    for (int i = 0; i < 4; ++i)
#pragma unroll
      for (int n = 0; n < 2; ++n)
#pragma unroll
        for (int s = 0; s < 2; ++s)
          acc[4 + i][2 + n] = __builtin_amdgcn_mfma_f32_16x16x32_bf16(a1[i][s], b[n][s], acc[4 + i][2 + n], 0, 0, 0);
#pragma unroll
    for (int i = 0; i < 4; ++i)
#pragma unroll
      for (int n = 0; n < 2; ++n)
#pragma unroll
        for (int s = 0; s < 2; ++s)
          acc[i][2 + n] = __builtin_amdgcn_mfma_f32_16x16x32_bf16(a0[i][s], b[n][s], acc[i][2 + n], 0, 0, 0);
    __builtin_amdgcn_s_setprio(0);

    SBAR();
    if (kt + 2 < 16) {
      STAGE(cur, kt + 2);
      asm volatile("s_waitcnt vmcnt(8)" ::: "memory");
    } else {
      asm volatile("s_waitcnt vmcnt(0)" ::: "memory");
    }
    SBAR();
  }
  #undef STAGE

  u16* out = gparts + (size_t)khalf * 2048 * 4096;
#pragma unroll
  for (int nf = 0; nf < 4; ++nf) {
    int col = n0 + wc * 64 + nf * 16 + lr;
#pragma unroll
    for (int mf = 0; mf < 8; ++mf)
#pragma unroll
      for (int r = 0; r < 4; ++r) {
        int row = m0 + wr * 128 + mf * 16 + l4 * 4 + r;
        out[(size_t)row * 4096 + col] = f2bf(acc[mf][nf][r]);
      }
  }
}

// ---------------- prepQ: query pack + Wq/Wk transposes (runs first) ----------
__global__ __launch_bounds__(256) void prepQ_k(
    const float* __restrict__ query, const float* __restrict__ Wq,
    const float* __restrict__ Wk,
    u16* __restrict__ qry, u16* __restrict__ wqtb, u16* __restrict__ wktb)
{
  __shared__ u16 tile[64][65];
  int blk = blockIdx.x;
  int t = threadIdx.x;
  if (blk < 2048) {                       // query pack
    int cc = t * 4;
    float4 v = *(const float4*)(query + (size_t)blk * 1024 + cc);
    ushort4 o; o.x = f2bf(v.x); o.y = f2bf(v.y); o.z = f2bf(v.z); o.w = f2bf(v.w);
    *(ushort4*)(qry + (size_t)blk * 1024 + cc) = o;
    return;
  }
  const float* src; u16* dst; int tblk;
  if (blk < 2304) { src = Wq; dst = wqtb; tblk = blk - 2048; }
  else            { src = Wk; dst = wktb; tblk = blk - 2304; }
  int tr = (tblk >> 4) * 64, tc = (tblk & 15) * 64;
  int tx = t & 63;
  int ty = (t >> 6) * 16;
#pragma unroll
  for (int i = 0; i < 16; ++i)
    tile[ty + i][tx] = f2bf(src[(size_t)(tr + ty + i) * 1024 + tc + tx]);
  __syncthreads();
#pragma unroll
  for (int i = 0; i < 16; ++i)
    dst[(size_t)(tc + ty + i) * 1024 + tr + tx] = tile[tx][ty + i];
}

// ---------------- prepRG: G gemm + bqwk hidden under remaining packs --------
__global__ __launch_bounds__(256) void prepRG_k(
    const float* __restrict__ pose, const float* __restrict__ h,
    const float* __restrict__ W_ih, const float* __restrict__ W_hh,
    const float* __restrict__ Wv,
    const u16* __restrict__ WkTb, const u16* __restrict__ WqTb,
    const float* __restrict__ bq, const float* __restrict__ Wk,
    u16* __restrict__ xcat, u16* __restrict__ wcat, u16* __restrict__ wvb,
    u16* __restrict__ Gb, float* __restrict__ qkb)
{
  __shared__ __align__(16) u16 As[128 * 32];
  __shared__ __align__(16) u16 Bs[128 * 32];
  const int blk = blockIdx.x;
  const int t = threadIdx.x;
  if (blk < 64) {
    const int lane = t & 63;
    const int w = t >> 6;
    const int wr = w >> 1, wc = w & 1;
    const int m0 = (blk >> 3) * 128, n0 = (blk & 7) * 128;
    const int lr = lane & 15;
    const int lk = (lane >> 4) * 8;
    const int srow = t >> 2;
    const int scol = (t & 3) * 8;
    const u16* gA = WkTb + (size_t)(m0 + srow) * 1024 + scol;
    const u16* gB = WqTb + (size_t)(n0 + srow) * 1024 + scol;
    f32x4 acc[4][4] = {};
    for (int k0 = 0; k0 < 1024; k0 += 32) {
      gl_lds16(gA,                     As + t * 8);
      gl_lds16(gA + (size_t)64 * 1024, As + 2048 + t * 8);
      gl_lds16(gB,                     Bs + t * 8);
      gl_lds16(gB + (size_t)64 * 1024, Bs + 2048 + t * 8);
      gA += 32; gB += 32;
      __syncthreads();
      short8 a[4], b[4];
#pragma unroll
      for (int m = 0; m < 4; ++m)
        a[m] = *(const short8*)(As + (wr * 64 + m * 16 + lr) * 32 + lk);
#pragma unroll
      for (int n = 0; n < 4; ++n)
        b[n] = *(const short8*)(Bs + (wc * 64 + n * 16 + lr) * 32 + lk);
#pragma unroll
      for (int m = 0; m < 4; ++m)
#pragma unroll
        for (int n = 0; n < 4; ++n)
          acc[m][n] = __builtin_amdgcn_mfma_f32_16x16x32_bf16(a[m], b[n], acc[m][n], 0, 0, 0);
      __syncthreads();
    }
#pragma unroll
    for (int n = 0; n < 4; ++n) {
      int col = n0 + wc * 64 + n * 16 + lr;
#pragma unroll
      for (int m = 0; m < 4; ++m)
#pragma unroll
        for (int r = 0; r < 4; ++r) {
          int row = m0 + wr * 64 + m * 16 + (lane >> 4) * 4 + r;
          Gb[(size_t)row * 1024 + col] = f2bf(acc[m][n][r]);
        }
    }
    return;
  }
  if (blk < 68) {
    int n = (blk - 64) * 256 + t;
    float s0 = 0.f, s1 = 0.f;
    for (int j = 0; j < 1024; j += 2) {
      s0 += bq[j]     * Wk[(size_t)j * 1024 + n];
      s1 += bq[j + 1] * Wk[(size_t)(j + 1) * 1024 + n];
    }
    qkb[n] = s0 + s1;
    return;
  }
  int b2 = blk - 68;
  const float* src; u16* dst; int ostride, ooff, base;
  if (b2 < 2048)       { src = pose;  dst = xcat; ostride = 2048; ooff = 0;    base = 0; }
  else if (b2 < 4096)  { src = h;     dst = xcat; ostride = 2048; ooff = 1024; base = 2048; }
  else if (b2 < 8192)  { src = W_ih;  dst = wcat; ostride = 2048; ooff = 0;    base = 4096; }
  else if (b2 < 12288) { src = W_hh;  dst = wcat; ostride = 2048; ooff = 1024; base = 8192; }
  else                 { src = Wv;    dst = wvb;  ostride = 1024; ooff = 0;    base = 12288; }
  int r = b2 - base;
  int cc = t * 4;
  float4 v = *(const float4*)(src + (size_t)r * 1024 + cc);
  ushort4 o; o.x = f2bf(v.x); o.y = f2bf(v.y); o.z = f2bf(v.z); o.w = f2bf(v.w);
  *(ushort4*)(dst + (size_t)r * ostride + ooff + cc) = o;
}

// ---------------- dedicated attention partial: rows 1..63, online softmax ----
__global__ __launch_bounds__(256) void attn_k(
    const float* __restrict__ Qk, const float* __restrict__ mem,
    float* __restrict__ attst)
{
  const int t = threadIdx.x;
  const int lane = t & 63;
  const int b = blockIdx.x * 4 + (t >> 6);
  const float* q = Qk + (size_t)b * 1024;
  f32x4 qv[4];
#pragma unroll
  for (int i = 0; i < 4; ++i)
    qv[i] = *(const f32x4*)(q + (i * 64 + lane) * 4);
  const float* mb = mem + (size_t)b * 65536;

  float m_run = -3e38f, l = 0.f;
  f32x4 cx[4] = {};

  for (int qd = 0; qd < 15; ++qd) {
    const float* r0 = mb + (size_t)(1 + qd * 4) * 1024;
    f32x4 rv[4][4];
    float s[4] = {0.f, 0.f, 0.f, 0.f};
#pragma unroll
    for (int rr = 0; rr < 4; ++rr)
#pragma unroll
      for (int i = 0; i < 4; ++i) {
        rv[rr][i] = __builtin_nontemporal_load(
            (const f32x4*)(r0 + rr * 1024 + (i * 64 + lane) * 4));
        s[rr] += rv[rr][i][0] * qv[i][0] + rv[rr][i][1] * qv[i][1] +
                 rv[rr][i][2] * qv[i][2] + rv[rr][i][3] * qv[i][3];
      }
#pragma unroll
    for (int rr = 0; rr < 4; ++rr) {
#pragma unroll
      for (int off = 32; off; off >>= 1) s[rr] += __shfl_xor(s[rr], off);
      s[rr] *= 0.03125f;
    }
#pragma unroll
    for (int rr = 0; rr < 4; ++rr) {
      if (s[rr] <= m_run + 8.f) {
        float e = __expf(s[rr] - m_run);
        l += e;
#pragma unroll
        for (int i = 0; i < 4; ++i) cx[i] += rv[rr][i] * e;
      } else {
        float sc = __expf(m_run - s[rr]);
        m_run = s[rr];
        l = l * sc + 1.f;
#pragma unroll
        for (int i = 0; i < 4; ++i) cx[i] = cx[i] * sc + rv[rr][i];
      }
    }
  }
  for (int r = 61; r <= 63; ++r) {
    const float* row = mb + (size_t)r * 1024;
    f32x4 rv[4];
    float s = 0.f;
#pragma unroll
    for (int i = 0; i < 4; ++i) {
      rv[i] = __builtin_nontemporal_load(
          (const f32x4*)(row + (i * 64 + lane) * 4));
      s += rv[i][0] * qv[i][0] + rv[i][1] * qv[i][1] +
           rv[i][2] * qv[i][2] + rv[i][3] * qv[i][3];
    }
#pragma unroll
    for (int off = 32; off; off >>= 1) s += __shfl_xor(s, off);
    s *= 0.03125f;
    if (s <= m_run + 8.f) {
      float e = __expf(s - m_run);
      l += e;
#pragma unroll
      for (int i = 0; i < 4; ++i) cx[i] += rv[i] * e;
    } else {
      float sc = __expf(m_run - s);
      m_run = s;
      l = l * sc + 1.f;
#pragma unroll
      for (int i = 0; i < 4; ++i) cx[i] = cx[i] * sc + rv[i];
    }
  }
  float* st = attst + (size_t)b * 1032;
#pragma unroll
  for (int i = 0; i < 4; ++i)
    *(f32x4*)(st + (i * 64 + lane) * 4) = cx[i];
  if (lane == 0) { st[1024] = m_run; st[1025] = l; }
}

// ---------------- fused LSTM elementwise + attention finish (partials) ------
__global__ __launch_bounds__(256) void lstmfin_k(
    const u16* __restrict__ gparts, const float* __restrict__ c,
    const float* __restrict__ b_ih, const float* __restrict__ b_hh,
    const float* __restrict__ Qk, const float* __restrict__ attst,
    float* __restrict__ out_h, float* __restrict__ out_c,
    u16* __restrict__ ctxb)
{
  const int b = blockIdx.x;
  const int t = threadIdx.x;
  const int lane = t & 63, wv_id = t >> 6;
  const int p = t * 4;
  const u16* g0 = gparts + (size_t)b * 4096;
  const u16* g1 = g0 + (size_t)2048 * 4096;
  float4 cv = *(const float4*)(c + (size_t)b * 1024 + p);
  float cvs[4] = {cv.x, cv.y, cv.z, cv.w};

  float hn[4], cn[4];
  float gsum[4][4];
#pragma unroll
  for (int gi = 0; gi < 4; ++gi) {
    ushort4 a = *(const ushort4*)(g0 + gi * 1024 + p);
    ushort4 bb = *(const ushort4*)(g1 + gi * 1024 + p);
    float4 bi = *(const float4*)(b_ih + gi * 1024 + p);
    float4 bh = *(const float4*)(b_hh + gi * 1024 + p);
    gsum[gi][0] = bf2f(a.x) + bf2f(bb.x) + bi.x + bh.x;
    gsum[gi][1] = bf2f(a.y) + bf2f(bb.y) + bi.y + bh.y;
    gsum[gi][2] = bf2f(a.z) + bf2f(bb.z) + bi.z + bh.z;
    gsum[gi][3] = bf2f(a.w) + bf2f(bb.w) + bi.w + bh.w;
  }
#pragma unroll
  for (int j = 0; j < 4; ++j) {
    float si = 1.f / (1.f + __expf(-gsum[0][j]));
    float sf = 1.f / (1.f + __expf(-gsum[1][j]));
    float so = 1.f / (1.f + __expf(-gsum[3][j]));
    float tg = 2.f / (1.f + __expf(-2.f * gsum[2][j])) - 1.f;
    cn[j] = sf * cvs[j] + si * tg;
    float tc2 = 2.f / (1.f + __expf(-2.f * cn[j])) - 1.f;
    hn[j] = so * tc2;
  }
  *(float4*)(out_c + (size_t)b * 1024 + p) = make_float4(cn[0], cn[1], cn[2], cn[3]);
  *(float4*)(out_h + (size_t)b * 1024 + p) = make_float4(hn[0], hn[1], hn[2], hn[3]);

  float4 qv = *(const float4*)(Qk + (size_t)b * 1024 + p);
  float part = qv.x * hn[0] + qv.y * hn[1] + qv.z * hn[2] + qv.w * hn[3];
#pragma unroll
  for (int off = 32; off; off >>= 1) part += __shfl_xor(part, off);
  __shared__ float red[4];
  if (lane == 0) red[wv_id] = part;
  __syncthreads();
  float s_last = (red[0] + red[1] + red[2] + red[3]) * 0.03125f;

  const float* st = attst + (size_t)b * 1032;
  float m_run = st[1024], l = st[1025];
  float4 cx = *(const float4*)(st + p);
  if (s_last <= m_run + 8.f) {
    float e = __expf(s_last - m_run);
    l += e;
    cx.x += e * hn[0]; cx.y += e * hn[1]; cx.z += e * hn[2]; cx.w += e * hn[3];
  } else {
    float sc = __expf(m_run - s_last);
    l = l * sc + 1.f;
    cx.x = cx.x * sc + hn[0]; cx.y = cx.y * sc + hn[1];
    cx.z = cx.z * sc + hn[2]; cx.w = cx.w * sc + hn[3];
  }
  float inv = 1.f / l;
  ushort4 o;
  o.x = f2bf(cx.x * inv); o.y = f2bf(cx.y * inv);
  o.z = f2bf(cx.z * inv); o.w = f2bf(cx.w * inv);
  *(ushort4*)(ctxb + (size_t)b * 1024 + p) = o;
}

extern "C" void kernel_launch(void* const* d_in, const int* in_sizes, int n_in,
                              void* d_out, int out_size, void* d_ws, size_t ws_size,
                              hipStream_t stream) {
  const int Bb = 2048, Hh = 1024;
  const float* pose  = (const float*)d_in[0];
  const float* query = (const float*)d_in[1];
  const float* h     = (const float*)d_in[2];
  const float* c     = (const float*)d_in[3];
  const float* mem   = (const float*)d_in[4];
  const float* W_ih  = (const float*)d_in[5];
  const float* W_hh  = (const float*)d_in[6];
  const float* b_ih  = (const float*)d_in[7];
  const float* b_hh  = (const float*)d_in[8];
  const float* Wq    = (const float*)d_in[9];
  const float* bq    = (const float*)d_in[10];
  const float* Wk    = (const float*)d_in[11];
  // d_in[12] = bk: m-independent score shift, cancels in softmax
  const float* Wv    = (const float*)d_in[13];
  const float* bv    = (const float*)d_in[14];

  float* out_att = (float*)d_out;
  float* out_h   = out_att + (size_t)Bb * Hh;
  float* out_c   = out_h + (size_t)Bb * Hh;

  char* wp = (char*)d_ws;
  auto alloc = [&](size_t bytes) {
    char* p = wp; wp += (bytes + 255) & ~(size_t)255; return p;
  };
  u16*   Xcat  = (u16*)alloc((size_t)2048 * 2048 * 2);   // 8 MB
  u16*   Wcat  = (u16*)alloc((size_t)4096 * 2048 * 2);   // 16 MB
  // next 4 contiguous, all dead before attn -> attst aliases them
  u16*   Qryb  = (u16*)alloc((size_t)2048 * 1024 * 2);   // 4 MB
  u16*   WqTb  = (u16*)alloc((size_t)1024 * 1024 * 2);   // 2 MB
  u16*   WkTb  = (u16*)alloc((size_t)1024 * 1024 * 2);   // 2 MB
  u16*   Gb    = (u16*)alloc((size_t)1024 * 1024 * 2);   // 2 MB
  u16*   Wvb   = (u16*)alloc((size_t)1024 * 1024 * 2);   // 2 MB (live through final)
  u16*   gparts= (u16*)alloc((size_t)2 * 2048 * 4096 * 2); // 32 MB (bf16 x2 halves)
  float* qkb   = (float*)alloc((size_t)1024 * 4);
  float* Qk    = (float*)alloc((size_t)2048 * 1024 * 4); // 8 MB
  u16*   ctxb  = (u16*)alloc((size_t)2048 * 1024 * 2);   // 4 MB
  float* attst = (float*)Qryb;   // [2048][1032] f32 = 8.45 MB < 10 MB alias pool

  // 1. prepQ: query pack + Wq/Wk transposes (feeds G)
  prepQ_k<<<2560, 256, 0, stream>>>(query, Wq, Wk, Qryb, WqTb, WkTb);

  // 2. prepRG: G gemm (64 blk) + bqwk (4 blk) hidden under packs (13312 blk)
  prepRG_k<<<13380, 256, 0, stream>>>(pose, h, W_ih, W_hh, Wv,
                                      WkTb, WqTb, bq, Wk,
                                      Xcat, Wcat, Wvb, Gb, qkb);

  // 3. Qk = query @ G^T + bq@Wk
  gemm_bt<<<dim3(8, 16), 256, 0, stream>>>(
      Qryb, Gb, Qk, nullptr, qkb, 2048, 1024, 1024);

  // 4. gates: 256^2 8-wave counted-vmcnt kernel (bank-conflict-free swizzle)
  gates8_k<<<256, 512, 0, stream>>>(Xcat, Wcat, gparts);

  // 5. attention partial solo (full-GPU streaming: 2048 waves)
  attn_k<<<512, 256, 0, stream>>>(Qk, mem, attst);

  // 6. LSTM elementwise (sum partials + biases) + attention finish -> ctx
  lstmfin_k<<<2048, 256, 0, stream>>>(gparts, c, b_ih, b_hh, Qk, attst,
                                      out_h, out_c, ctxb);

  // 7. attended = ctx @ Wv^T + bv
  gemm_bt<<<dim3(8, 16), 256, 0, stream>>>(
      ctxb, Wvb, out_att, nullptr, bv, 2048, 1024, 1024);
}

// Round 16
// 225.967 us; speedup vs baseline: 1.1821x; 1.0550x over previous
//
#include <hip/hip_runtime.h>
#include <stdint.h>

typedef __attribute__((ext_vector_type(8))) short short8;
typedef __attribute__((ext_vector_type(4))) float f32x4;
typedef unsigned short u16;

#define SBAR() do { __builtin_amdgcn_sched_barrier(0); \
                    __builtin_amdgcn_s_barrier(); \
                    __builtin_amdgcn_sched_barrier(0); } while (0)

__device__ __forceinline__ u16 f2bf(float f) {
  union { float f; uint32_t u; } v; v.f = f;
  return (u16)((v.u + 0x7FFFu + ((v.u >> 16) & 1u)) >> 16);
}
__device__ __forceinline__ float bf2f(u16 u) {
  union { uint32_t u; float f; } v; v.u = (uint32_t)u << 16; return v.f;
}

__device__ __forceinline__ void gl_lds16(const void* g, void* l) {
  __builtin_amdgcn_global_load_lds(
      (const __attribute__((address_space(1))) void*)g,
      (__attribute__((address_space(3))) void*)l, 16, 0, 0);
}

// -------- skinny GEMM: 64x128 tiles -> 256 blocks at M=2048,N=1024 ----------
// C[M,N] = A[M,K](bf16) @ B[N,K](bf16)^T (+bias); f32 and/or bf16 out.
// 4 waves: wr=w>>1 (32-row slice), wc=w&1 (64-col slice); acc[2][4].
// ALL gl_lds16 destinations are strictly (uniform base + lane*16B) — the
// HW constraint that R15 violated (B had a 32B/lane stride -> NaN).
__global__ __launch_bounds__(256) void gemm64_k(
    const u16* __restrict__ A, const u16* __restrict__ B,
    float* __restrict__ Cf, u16* __restrict__ Cb,
    const float* __restrict__ bias1,
    int M, int N, int K)
{
  __shared__ __align__(16) u16 As[64 * 32];    // 4 KB
  __shared__ __align__(16) u16 Bs[128 * 32];   // 8 KB
  const int t = threadIdx.x;
  const int lane = t & 63;
  const int w = t >> 6;
  const int wr = w >> 1, wc = w & 1;
  const int m0 = blockIdx.y * 64, n0 = blockIdx.x * 128;
  const int lr = lane & 15;
  const int lk = (lane >> 4) * 8;
  const int srow = t >> 2;          // 0..63
  const int scol = (t & 3) * 8;     // {0,8,16,24}

  const u16* gA = A + (size_t)(m0 + srow) * K + scol;   // 64 rows
  const u16* gB = B + (size_t)(n0 + srow) * K + scol;   // rows 0..63 (+64 half)

  f32x4 acc[2][4] = {};

  for (int k0 = 0; k0 < K; k0 += 32) {
    gl_lds16(gA,                  As + t * 8);
    gl_lds16(gB,                  Bs + t * 8);
    gl_lds16(gB + (size_t)64 * K, Bs + 2048 + t * 8);
    gA += 32; gB += 32;
    __syncthreads();

    short8 a[2], b[4];
#pragma unroll
    for (int m = 0; m < 2; ++m)
      a[m] = *(const short8*)(As + (wr * 32 + m * 16 + lr) * 32 + lk);
#pragma unroll
    for (int n = 0; n < 4; ++n)
      b[n] = *(const short8*)(Bs + (wc * 64 + n * 16 + lr) * 32 + lk);
#pragma unroll
    for (int m = 0; m < 2; ++m)
#pragma unroll
      for (int n = 0; n < 4; ++n)
        acc[m][n] = __builtin_amdgcn_mfma_f32_16x16x32_bf16(a[m], b[n], acc[m][n], 0, 0, 0);
    __syncthreads();
  }

#pragma unroll
  for (int n = 0; n < 4; ++n) {
    int col = n0 + wc * 64 + n * 16 + lr;
    float bsum = bias1 ? bias1[col] : 0.f;
#pragma unroll
    for (int m = 0; m < 2; ++m) {
#pragma unroll
      for (int r = 0; r < 4; ++r) {
        int row = m0 + wr * 32 + m * 16 + (lane >> 4) * 4 + r;
        float vv = acc[m][n][r] + bsum;
        if (Cf) Cf[(size_t)row * N + col] = vv;
        if (Cb) Cb[(size_t)row * N + col] = f2bf(vv);
      }
    }
  }
}

// ---------------- gates GEMM: 256x256, BK=64, 8-wave, counted-vmcnt ----------
// (verbatim R14: bank-uniform 3-bit row swizzle, K-split x2, 256 blk x 512 t)
__global__ __launch_bounds__(512) void gates8_k(
    const u16* __restrict__ Xcat, const u16* __restrict__ Wcat,
    u16* __restrict__ gparts)
{
  __shared__ __align__(16) u16 lds[65536];     // 128 KB
  const int t = threadIdx.x;
  const int l = t & 63;
  const int w = t >> 6;
  const int wr = w >> 2, wc = w & 3;
  const int bid = blockIdx.x;
  const int tile = bid >> 1, khalf = bid & 1;
  const int m0 = (tile >> 4) * 256;
  const int n0 = (tile & 15) * 256;
  const int lr = l & 15;
  const int l4 = l >> 4;

  const int sr = l >> 3;
  const int sc = ((l & 7) * 8) ^ (((((l >> 4) & 3) | ((w & 1) << 2))) << 3);

  const u16* Abase = Xcat + (size_t)m0 * 2048 + khalf * 1024 + sc;
  const u16* Bbase = Wcat + (size_t)n0 * 2048 + khalf * 1024 + sc;

  #define STAGE(buf, kt) do {                                                  \
    const int kof_ = (kt) * 64;                                                \
    _Pragma("unroll")                                                          \
    for (int hh = 0; hh < 2; ++hh)                                             \
      _Pragma("unroll")                                                        \
      for (int j = 0; j < 2; ++j) {                                            \
        int row_ = hh * 128 + (w + 8 * j) * 8 + sr;                            \
        char* dA = (char*)lds + (buf) * 65536 + hh * 16384 + (w + 8*j) * 1024 + l * 16; \
        char* dB = dA + 32768;                                                 \
        gl_lds16(Abase + (size_t)row_ * 2048 + kof_, dA);                      \
        gl_lds16(Bbase + (size_t)row_ * 2048 + kof_, dB);                      \
      }                                                                        \
  } while (0)

  auto LDA = [&](int buf, int mf, int s) -> short8 {
    int rr = mf * 16 + lr;
    int cb = (s * 64 + l4 * 16) ^ (((lr >> 1) & 7) << 4);
    return *(const short8*)((const char*)lds + buf * 65536 + wr * 16384 + rr * 128 + cb);
  };
  auto LDB = [&](int buf, int nf, int s) -> short8 {
    int rr = (wc & 1) * 64 + nf * 16 + lr;
    int cb = (s * 64 + l4 * 16) ^ (((lr >> 1) & 7) << 4);
    return *(const short8*)((const char*)lds + buf * 65536 + 32768 + (wc >> 1) * 16384 + rr * 128 + cb);
  };

  f32x4 acc[8][4] = {};

  STAGE(0, 0);
  STAGE(1, 1);
  asm volatile("s_waitcnt vmcnt(8)" ::: "memory");
  SBAR();

  for (int kt = 0; kt < 16; ++kt) {
    const int cur = kt & 1;
    short8 a0[4][2], a1[4][2], b[2][2];
#pragma unroll
    for (int i = 0; i < 4; ++i) { a0[i][0] = LDA(cur, i, 0); a0[i][1] = LDA(cur, i, 1); }
#pragma unroll
    for (int n = 0; n < 2; ++n) { b[n][0] = LDB(cur, n, 0); b[n][1] = LDB(cur, n, 1); }
    __builtin_amdgcn_s_setprio(1);
#pragma unroll
    for (int i = 0; i < 4; ++i)
#pragma unroll
      for (int n = 0; n < 2; ++n)
#pragma unroll
        for (int s = 0; s < 2; ++s)
          acc[i][n] = __builtin_amdgcn_mfma_f32_16x16x32_bf16(a0[i][s], b[n][s], acc[i][n], 0, 0, 0);
    __builtin_amdgcn_s_setprio(0);
#pragma unroll
    for (int i = 0; i < 4; ++i) { a1[i][0] = LDA(cur, 4 + i, 0); a1[i][1] = LDA(cur, 4 + i, 1); }
    __builtin_amdgcn_s_setprio(1);
#pragma unroll
    for (int i = 0; i < 4; ++i)
#pragma unroll
      for (int n = 0; n < 2; ++n)
#pragma unroll
        for (int s = 0; s < 2; ++s)
          acc[4 + i][n] = __builtin_amdgcn_mfma_f32_16x16x32_bf16(a1[i][s], b[n][s], acc[4 + i][n], 0, 0, 0);
    __builtin_amdgcn_s_setprio(0);
#pragma unroll
    for (int n = 0; n < 2; ++n) { b[n][0] = LDB(cur, 2 + n, 0); b[n][1] = LDB(cur, 2 + n, 1); }
    __builtin_amdgcn_s_setprio(1);
#pragma unroll
    for (int i = 0; i < 4; ++i)
#pragma unroll
      for (int n = 0; n < 2; ++n)
#pragma unroll
        for (int s = 0; s < 2; ++s)
          acc[4 + i][2 + n] = __builtin_amdgcn_mfma_f32_16x16x32_bf16(a1[i][s], b[n][s], acc[4 + i][2 + n], 0, 0, 0);
#pragma unroll
    for (int i = 0; i < 4; ++i)
#pragma unroll
      for (int n = 0; n < 2; ++n)
#pragma unroll
        for (int s = 0; s < 2; ++s)
          acc[i][2 + n] = __builtin_amdgcn_mfma_f32_16x16x32_bf16(a0[i][s], b[n][s], acc[i][2 + n], 0, 0, 0);
    __builtin_amdgcn_s_setprio(0);

    SBAR();
    if (kt + 2 < 16) {
      STAGE(cur, kt + 2);
      asm volatile("s_waitcnt vmcnt(8)" ::: "memory");
    } else {
      asm volatile("s_waitcnt vmcnt(0)" ::: "memory");
    }
    SBAR();
  }
  #undef STAGE

  u16* out = gparts + (size_t)khalf * 2048 * 4096;
#pragma unroll
  for (int nf = 0; nf < 4; ++nf) {
    int col = n0 + wc * 64 + nf * 16 + lr;
#pragma unroll
    for (int mf = 0; mf < 8; ++mf)
#pragma unroll
      for (int r = 0; r < 4; ++r) {
        int row = m0 + wr * 128 + mf * 16 + l4 * 4 + r;
        out[(size_t)row * 4096 + col] = f2bf(acc[mf][nf][r]);
      }
  }
}

// ---------------- prepQ: query pack + Wq/Wk transposes (runs first) ----------
__global__ __launch_bounds__(256) void prepQ_k(
    const float* __restrict__ query, const float* __restrict__ Wq,
    const float* __restrict__ Wk,
    u16* __restrict__ qry, u16* __restrict__ wqtb, u16* __restrict__ wktb)
{
  __shared__ u16 tile[64][65];
  int blk = blockIdx.x;
  int t = threadIdx.x;
  if (blk < 2048) {
    int cc = t * 4;
    float4 v = *(const float4*)(query + (size_t)blk * 1024 + cc);
    ushort4 o; o.x = f2bf(v.x); o.y = f2bf(v.y); o.z = f2bf(v.z); o.w = f2bf(v.w);
    *(ushort4*)(qry + (size_t)blk * 1024 + cc) = o;
    return;
  }
  const float* src; u16* dst; int tblk;
  if (blk < 2304) { src = Wq; dst = wqtb; tblk = blk - 2048; }
  else            { src = Wk; dst = wktb; tblk = blk - 2304; }
  int tr = (tblk >> 4) * 64, tc = (tblk & 15) * 64;
  int tx = t & 63;
  int ty = (t >> 6) * 16;
#pragma unroll
  for (int i = 0; i < 16; ++i)
    tile[ty + i][tx] = f2bf(src[(size_t)(tr + ty + i) * 1024 + tc + tx]);
  __syncthreads();
#pragma unroll
  for (int i = 0; i < 16; ++i)
    dst[(size_t)(tc + ty + i) * 1024 + tr + tx] = tile[tx][ty + i];
}

// ---------------- prepRG: G gemm + bqwk hidden under remaining packs --------
__global__ __launch_bounds__(256) void prepRG_k(
    const float* __restrict__ pose, const float* __restrict__ h,
    const float* __restrict__ W_ih, const float* __restrict__ W_hh,
    const float* __restrict__ Wv,
    const u16* __restrict__ WkTb, const u16* __restrict__ WqTb,
    const float* __restrict__ bq, const float* __restrict__ Wk,
    u16* __restrict__ xcat, u16* __restrict__ wcat, u16* __restrict__ wvb,
    u16* __restrict__ Gb, float* __restrict__ qkb)
{
  __shared__ __align__(16) u16 As[128 * 32];
  __shared__ __align__(16) u16 Bs[128 * 32];
  const int blk = blockIdx.x;
  const int t = threadIdx.x;
  if (blk < 64) {
    const int lane = t & 63;
    const int w = t >> 6;
    const int wr = w >> 1, wc = w & 1;
    const int m0 = (blk >> 3) * 128, n0 = (blk & 7) * 128;
    const int lr = lane & 15;
    const int lk = (lane >> 4) * 8;
    const int srow = t >> 2;
    const int scol = (t & 3) * 8;
    const u16* gA = WkTb + (size_t)(m0 + srow) * 1024 + scol;
    const u16* gB = WqTb + (size_t)(n0 + srow) * 1024 + scol;
    f32x4 acc[4][4] = {};
    for (int k0 = 0; k0 < 1024; k0 += 32) {
      gl_lds16(gA,                     As + t * 8);
      gl_lds16(gA + (size_t)64 * 1024, As + 2048 + t * 8);
      gl_lds16(gB,                     Bs + t * 8);
      gl_lds16(gB + (size_t)64 * 1024, Bs + 2048 + t * 8);
      gA += 32; gB += 32;
      __syncthreads();
      short8 a[4], b[4];
#pragma unroll
      for (int m = 0; m < 4; ++m)
        a[m] = *(const short8*)(As + (wr * 64 + m * 16 + lr) * 32 + lk);
#pragma unroll
      for (int n = 0; n < 4; ++n)
        b[n] = *(const short8*)(Bs + (wc * 64 + n * 16 + lr) * 32 + lk);
#pragma unroll
      for (int m = 0; m < 4; ++m)
#pragma unroll
        for (int n = 0; n < 4; ++n)
          acc[m][n] = __builtin_amdgcn_mfma_f32_16x16x32_bf16(a[m], b[n], acc[m][n], 0, 0, 0);
      __syncthreads();
    }
#pragma unroll
    for (int n = 0; n < 4; ++n) {
      int col = n0 + wc * 64 + n * 16 + lr;
#pragma unroll
      for (int m = 0; m < 4; ++m)
#pragma unroll
        for (int r = 0; r < 4; ++r) {
          int row = m0 + wr * 64 + m * 16 + (lane >> 4) * 4 + r;
          Gb[(size_t)row * 1024 + col] = f2bf(acc[m][n][r]);
        }
    }
    return;
  }
  if (blk < 68) {
    int n = (blk - 64) * 256 + t;
    float s0 = 0.f, s1 = 0.f;
    for (int j = 0; j < 1024; j += 2) {
      s0 += bq[j]     * Wk[(size_t)j * 1024 + n];
      s1 += bq[j + 1] * Wk[(size_t)(j + 1) * 1024 + n];
    }
    qkb[n] = s0 + s1;
    return;
  }
  int b2 = blk - 68;
  const float* src; u16* dst; int ostride, ooff, base;
  if (b2 < 2048)       { src = pose;  dst = xcat; ostride = 2048; ooff = 0;    base = 0; }
  else if (b2 < 4096)  { src = h;     dst = xcat; ostride = 2048; ooff = 1024; base = 2048; }
  else if (b2 < 8192)  { src = W_ih;  dst = wcat; ostride = 2048; ooff = 0;    base = 4096; }
  else if (b2 < 12288) { src = W_hh;  dst = wcat; ostride = 2048; ooff = 1024; base = 8192; }
  else                 { src = Wv;    dst = wvb;  ostride = 1024; ooff = 0;    base = 12288; }
  int r = b2 - base;
  int cc = t * 4;
  float4 v = *(const float4*)(src + (size_t)r * 1024 + cc);
  ushort4 o; o.x = f2bf(v.x); o.y = f2bf(v.y); o.z = f2bf(v.z); o.w = f2bf(v.w);
  *(ushort4*)(dst + (size_t)r * ostride + ooff + cc) = o;
}

// ---------------- dedicated attention partial: rows 1..63, online softmax ----
__global__ __launch_bounds__(256) void attn_k(
    const float* __restrict__ Qk, const float* __restrict__ mem,
    float* __restrict__ attst)
{
  const int t = threadIdx.x;
  const int lane = t & 63;
  const int b = blockIdx.x * 4 + (t >> 6);
  const float* q = Qk + (size_t)b * 1024;
  f32x4 qv[4];
#pragma unroll
  for (int i = 0; i < 4; ++i)
    qv[i] = *(const f32x4*)(q + (i * 64 + lane) * 4);
  const float* mb = mem + (size_t)b * 65536;

  float m_run = -3e38f, l = 0.f;
  f32x4 cx[4] = {};

  for (int qd = 0; qd < 15; ++qd) {
    const float* r0 = mb + (size_t)(1 + qd * 4) * 1024;
    f32x4 rv[4][4];
    float s[4] = {0.f, 0.f, 0.f, 0.f};
#pragma unroll
    for (int rr = 0; rr < 4; ++rr)
#pragma unroll
      for (int i = 0; i < 4; ++i) {
        rv[rr][i] = __builtin_nontemporal_load(
            (const f32x4*)(r0 + rr * 1024 + (i * 64 + lane) * 4));
        s[rr] += rv[rr][i][0] * qv[i][0] + rv[rr][i][1] * qv[i][1] +
                 rv[rr][i][2] * qv[i][2] + rv[rr][i][3] * qv[i][3];
      }
#pragma unroll
    for (int rr = 0; rr < 4; ++rr) {
#pragma unroll
      for (int off = 32; off; off >>= 1) s[rr] += __shfl_xor(s[rr], off);
      s[rr] *= 0.03125f;
    }
#pragma unroll
    for (int rr = 0; rr < 4; ++rr) {
      if (s[rr] <= m_run + 8.f) {
        float e = __expf(s[rr] - m_run);
        l += e;
#pragma unroll
        for (int i = 0; i < 4; ++i) cx[i] += rv[rr][i] * e;
      } else {
        float sc = __expf(m_run - s[rr]);
        m_run = s[rr];
        l = l * sc + 1.f;
#pragma unroll
        for (int i = 0; i < 4; ++i) cx[i] = cx[i] * sc + rv[rr][i];
      }
    }
  }
  for (int r = 61; r <= 63; ++r) {
    const float* row = mb + (size_t)r * 1024;
    f32x4 rv[4];
    float s = 0.f;
#pragma unroll
    for (int i = 0; i < 4; ++i) {
      rv[i] = __builtin_nontemporal_load(
          (const f32x4*)(row + (i * 64 + lane) * 4));
      s += rv[i][0] * qv[i][0] + rv[i][1] * qv[i][1] +
           rv[i][2] * qv[i][2] + rv[i][3] * qv[i][3];
    }
#pragma unroll
    for (int off = 32; off; off >>= 1) s += __shfl_xor(s, off);
    s *= 0.03125f;
    if (s <= m_run + 8.f) {
      float e = __expf(s - m_run);
      l += e;
#pragma unroll
      for (int i = 0; i < 4; ++i) cx[i] += rv[i] * e;
    } else {
      float sc = __expf(m_run - s);
      m_run = s;
      l = l * sc + 1.f;
#pragma unroll
      for (int i = 0; i < 4; ++i) cx[i] = cx[i] * sc + rv[i];
    }
  }
  float* st = attst + (size_t)b * 1032;
#pragma unroll
  for (int i = 0; i < 4; ++i)
    *(f32x4*)(st + (i * 64 + lane) * 4) = cx[i];
  if (lane == 0) { st[1024] = m_run; st[1025] = l; }
}

// ---------------- fused LSTM elementwise + attention finish (partials) ------
__global__ __launch_bounds__(256) void lstmfin_k(
    const u16* __restrict__ gparts, const float* __restrict__ c,
    const float* __restrict__ b_ih, const float* __restrict__ b_hh,
    const float* __restrict__ Qk, const float* __restrict__ attst,
    float* __restrict__ out_h, float* __restrict__ out_c,
    u16* __restrict__ ctxb)
{
  const int b = blockIdx.x;
  const int t = threadIdx.x;
  const int lane = t & 63, wv_id = t >> 6;
  const int p = t * 4;
  const u16* g0 = gparts + (size_t)b * 4096;
  const u16* g1 = g0 + (size_t)2048 * 4096;
  float4 cv = *(const float4*)(c + (size_t)b * 1024 + p);
  float cvs[4] = {cv.x, cv.y, cv.z, cv.w};

  float hn[4], cn[4];
  float gsum[4][4];
#pragma unroll
  for (int gi = 0; gi < 4; ++gi) {
    ushort4 a = *(const ushort4*)(g0 + gi * 1024 + p);
    ushort4 bb = *(const ushort4*)(g1 + gi * 1024 + p);
    float4 bi = *(const float4*)(b_ih + gi * 1024 + p);
    float4 bh = *(const float4*)(b_hh + gi * 1024 + p);
    gsum[gi][0] = bf2f(a.x) + bf2f(bb.x) + bi.x + bh.x;
    gsum[gi][1] = bf2f(a.y) + bf2f(bb.y) + bi.y + bh.y;
    gsum[gi][2] = bf2f(a.z) + bf2f(bb.z) + bi.z + bh.z;
    gsum[gi][3] = bf2f(a.w) + bf2f(bb.w) + bi.w + bh.w;
  }
#pragma unroll
  for (int j = 0; j < 4; ++j) {
    float si = 1.f / (1.f + __expf(-gsum[0][j]));
    float sf = 1.f / (1.f + __expf(-gsum[1][j]));
    float so = 1.f / (1.f + __expf(-gsum[3][j]));
    float tg = 2.f / (1.f + __expf(-2.f * gsum[2][j])) - 1.f;
    cn[j] = sf * cvs[j] + si * tg;
    float tc2 = 2.f / (1.f + __expf(-2.f * cn[j])) - 1.f;
    hn[j] = so * tc2;
  }
  *(float4*)(out_c + (size_t)b * 1024 + p) = make_float4(cn[0], cn[1], cn[2], cn[3]);
  *(float4*)(out_h + (size_t)b * 1024 + p) = make_float4(hn[0], hn[1], hn[2], hn[3]);

  float4 qv = *(const float4*)(Qk + (size_t)b * 1024 + p);
  float part = qv.x * hn[0] + qv.y * hn[1] + qv.z * hn[2] + qv.w * hn[3];
#pragma unroll
  for (int off = 32; off; off >>= 1) part += __shfl_xor(part, off);
  __shared__ float red[4];
  if (lane == 0) red[wv_id] = part;
  __syncthreads();
  float s_last = (red[0] + red[1] + red[2] + red[3]) * 0.03125f;

  const float* st = attst + (size_t)b * 1032;
  float m_run = st[1024], l = st[1025];
  float4 cx = *(const float4*)(st + p);
  if (s_last <= m_run + 8.f) {
    float e = __expf(s_last - m_run);
    l += e;
    cx.x += e * hn[0]; cx.y += e * hn[1]; cx.z += e * hn[2]; cx.w += e * hn[3];
  } else {
    float sc = __expf(m_run - s_last);
    l = l * sc + 1.f;
    cx.x = cx.x * sc + hn[0]; cx.y = cx.y * sc + hn[1];
    cx.z = cx.z * sc + hn[2]; cx.w = cx.w * sc + hn[3];
  }
  float inv = 1.f / l;
  ushort4 o;
  o.x = f2bf(cx.x * inv); o.y = f2bf(cx.y * inv);
  o.z = f2bf(cx.z * inv); o.w = f2bf(cx.w * inv);
  *(ushort4*)(ctxb + (size_t)b * 1024 + p) = o;
}

extern "C" void kernel_launch(void* const* d_in, const int* in_sizes, int n_in,
                              void* d_out, int out_size, void* d_ws, size_t ws_size,
                              hipStream_t stream) {
  const int Bb = 2048, Hh = 1024;
  const float* pose  = (const float*)d_in[0];
  const float* query = (const float*)d_in[1];
  const float* h     = (const float*)d_in[2];
  const float* c     = (const float*)d_in[3];
  const float* mem   = (const float*)d_in[4];
  const float* W_ih  = (const float*)d_in[5];
  const float* W_hh  = (const float*)d_in[6];
  const float* b_ih  = (const float*)d_in[7];
  const float* b_hh  = (const float*)d_in[8];
  const float* Wq    = (const float*)d_in[9];
  const float* bq    = (const float*)d_in[10];
  const float* Wk    = (const float*)d_in[11];
  // d_in[12] = bk: m-independent score shift, cancels in softmax
  const float* Wv    = (const float*)d_in[13];
  const float* bv    = (const float*)d_in[14];

  float* out_att = (float*)d_out;
  float* out_h   = out_att + (size_t)Bb * Hh;
  float* out_c   = out_h + (size_t)Bb * Hh;

  char* wp = (char*)d_ws;
  auto alloc = [&](size_t bytes) {
    char* p = wp; wp += (bytes + 255) & ~(size_t)255; return p;
  };
  u16*   Xcat  = (u16*)alloc((size_t)2048 * 2048 * 2);   // 8 MB
  u16*   Wcat  = (u16*)alloc((size_t)4096 * 2048 * 2);   // 16 MB
  // next 4 contiguous, all dead before attn -> attst aliases them
  u16*   Qryb  = (u16*)alloc((size_t)2048 * 1024 * 2);   // 4 MB
  u16*   WqTb  = (u16*)alloc((size_t)1024 * 1024 * 2);   // 2 MB
  u16*   WkTb  = (u16*)alloc((size_t)1024 * 1024 * 2);   // 2 MB
  u16*   Gb    = (u16*)alloc((size_t)1024 * 1024 * 2);   // 2 MB
  u16*   Wvb   = (u16*)alloc((size_t)1024 * 1024 * 2);   // 2 MB (live through final)
  u16*   gparts= (u16*)alloc((size_t)2 * 2048 * 4096 * 2); // 32 MB (bf16 x2 halves)
  float* qkb   = (float*)alloc((size_t)1024 * 4);
  float* Qk    = (float*)alloc((size_t)2048 * 1024 * 4); // 8 MB
  u16*   ctxb  = (u16*)alloc((size_t)2048 * 1024 * 2);   // 4 MB
  float* attst = (float*)Qryb;   // [2048][1032] f32 = 8.45 MB < 10 MB alias pool

  // 1. prepQ: query pack + Wq/Wk transposes (feeds G)
  prepQ_k<<<2560, 256, 0, stream>>>(query, Wq, Wk, Qryb, WqTb, WkTb);

  // 2. prepRG: G gemm (64 blk) + bqwk (4 blk) hidden under packs (13312 blk)
  prepRG_k<<<13380, 256, 0, stream>>>(pose, h, W_ih, W_hh, Wv,
                                      WkTb, WqTb, bq, Wk,
                                      Xcat, Wcat, Wvb, Gb, qkb);

  // 3. Qk = query @ G^T + bq@Wk  (64x128 tiles -> 256 blocks, full GPU)
  gemm64_k<<<dim3(8, 32), 256, 0, stream>>>(
      Qryb, Gb, Qk, nullptr, qkb, 2048, 1024, 1024);

  // 4. gates: 256^2 8-wave counted-vmcnt kernel (bank-uniform swizzle)
  gates8_k<<<256, 512, 0, stream>>>(Xcat, Wcat, gparts);

  // 5. attention partial solo (full-GPU streaming: 2048 waves)
  attn_k<<<512, 256, 0, stream>>>(Qk, mem, attst);

  // 6. LSTM elementwise (sum partials + biases) + attention finish -> ctx
  lstmfin_k<<<2048, 256, 0, stream>>>(gparts, c, b_ih, b_hh, Qk, attst,
                                      out_h, out_c, ctxb);

  // 7. attended = ctx @ Wv^T + bv  (64x128 tiles -> 256 blocks, full GPU)
  gemm64_k<<<dim3(8, 32), 256, 0, stream>>>(
      ctxb, Wvb, out_att, nullptr, bv, 2048, 1024, 1024);
}

// Round 17
// 224.074 us; speedup vs baseline: 1.1921x; 1.0084x over previous
//
#include <hip/hip_runtime.h>
#include <stdint.h>

typedef __attribute__((ext_vector_type(8))) short short8;
typedef __attribute__((ext_vector_type(4))) float f32x4;
typedef unsigned short u16;

#define SBAR() do { __builtin_amdgcn_sched_barrier(0); \
                    __builtin_amdgcn_s_barrier(); \
                    __builtin_amdgcn_sched_barrier(0); } while (0)

__device__ __forceinline__ u16 f2bf(float f) {
  union { float f; uint32_t u; } v; v.f = f;
  return (u16)((v.u + 0x7FFFu + ((v.u >> 16) & 1u)) >> 16);
}
__device__ __forceinline__ float bf2f(u16 u) {
  union { uint32_t u; float f; } v; v.u = (uint32_t)u << 16; return v.f;
}

__device__ __forceinline__ void gl_lds16(const void* g, void* l) {
  __builtin_amdgcn_global_load_lds(
      (const __attribute__((address_space(1))) void*)g,
      (__attribute__((address_space(3))) void*)l, 16, 0, 0);
}

// -------- skinny GEMM: 64x128 tiles -> 256 blocks at M=2048,N=1024 ----------
// All gl_lds16 destinations strictly (uniform base + lane*16B).
__global__ __launch_bounds__(256) void gemm64_k(
    const u16* __restrict__ A, const u16* __restrict__ B,
    float* __restrict__ Cf, u16* __restrict__ Cb,
    const float* __restrict__ bias1,
    int M, int N, int K)
{
  __shared__ __align__(16) u16 As[64 * 32];    // 4 KB
  __shared__ __align__(16) u16 Bs[128 * 32];   // 8 KB
  const int t = threadIdx.x;
  const int lane = t & 63;
  const int w = t >> 6;
  const int wr = w >> 1, wc = w & 1;
  const int m0 = blockIdx.y * 64, n0 = blockIdx.x * 128;
  const int lr = lane & 15;
  const int lk = (lane >> 4) * 8;
  const int srow = t >> 2;
  const int scol = (t & 3) * 8;

  const u16* gA = A + (size_t)(m0 + srow) * K + scol;
  const u16* gB = B + (size_t)(n0 + srow) * K + scol;

  f32x4 acc[2][4] = {};

  for (int k0 = 0; k0 < K; k0 += 32) {
    gl_lds16(gA,                  As + t * 8);
    gl_lds16(gB,                  Bs + t * 8);
    gl_lds16(gB + (size_t)64 * K, Bs + 2048 + t * 8);
    gA += 32; gB += 32;
    __syncthreads();

    short8 a[2], b[4];
#pragma unroll
    for (int m = 0; m < 2; ++m)
      a[m] = *(const short8*)(As + (wr * 32 + m * 16 + lr) * 32 + lk);
#pragma unroll
    for (int n = 0; n < 4; ++n)
      b[n] = *(const short8*)(Bs + (wc * 64 + n * 16 + lr) * 32 + lk);
#pragma unroll
    for (int m = 0; m < 2; ++m)
#pragma unroll
      for (int n = 0; n < 4; ++n)
        acc[m][n] = __builtin_amdgcn_mfma_f32_16x16x32_bf16(a[m], b[n], acc[m][n], 0, 0, 0);
    __syncthreads();
  }

#pragma unroll
  for (int n = 0; n < 4; ++n) {
    int col = n0 + wc * 64 + n * 16 + lr;
    float bsum = bias1 ? bias1[col] : 0.f;
#pragma unroll
    for (int m = 0; m < 2; ++m) {
#pragma unroll
      for (int r = 0; r < 4; ++r) {
        int row = m0 + wr * 32 + m * 16 + (lane >> 4) * 4 + r;
        float vv = acc[m][n][r] + bsum;
        if (Cf) Cf[(size_t)row * N + col] = vv;
        if (Cb) Cb[(size_t)row * N + col] = f2bf(vv);
      }
    }
  }
}

// ---------------- gates GEMM: 256x256, BK=64, 8-wave, counted-vmcnt ----------
// (verbatim R14/R16: bank-uniform row swizzle, K-split x2, 256 blk x 512 t)
__global__ __launch_bounds__(512) void gates8_k(
    const u16* __restrict__ Xcat, const u16* __restrict__ Wcat,
    u16* __restrict__ gparts)
{
  __shared__ __align__(16) u16 lds[65536];     // 128 KB
  const int t = threadIdx.x;
  const int l = t & 63;
  const int w = t >> 6;
  const int wr = w >> 2, wc = w & 3;
  const int bid = blockIdx.x;
  const int tile = bid >> 1, khalf = bid & 1;
  const int m0 = (tile >> 4) * 256;
  const int n0 = (tile & 15) * 256;
  const int lr = l & 15;
  const int l4 = l >> 4;

  const int sr = l >> 3;
  const int sc = ((l & 7) * 8) ^ (((((l >> 4) & 3) | ((w & 1) << 2))) << 3);

  const u16* Abase = Xcat + (size_t)m0 * 2048 + khalf * 1024 + sc;
  const u16* Bbase = Wcat + (size_t)n0 * 2048 + khalf * 1024 + sc;

  #define STAGE(buf, kt) do {                                                  \
    const int kof_ = (kt) * 64;                                                \
    _Pragma("unroll")                                                          \
    for (int hh = 0; hh < 2; ++hh)                                             \
      _Pragma("unroll")                                                        \
      for (int j = 0; j < 2; ++j) {                                            \
        int row_ = hh * 128 + (w + 8 * j) * 8 + sr;                            \
        char* dA = (char*)lds + (buf) * 65536 + hh * 16384 + (w + 8*j) * 1024 + l * 16; \
        char* dB = dA + 32768;                                                 \
        gl_lds16(Abase + (size_t)row_ * 2048 + kof_, dA);                      \
        gl_lds16(Bbase + (size_t)row_ * 2048 + kof_, dB);                      \
      }                                                                        \
  } while (0)

  auto LDA = [&](int buf, int mf, int s) -> short8 {
    int rr = mf * 16 + lr;
    int cb = (s * 64 + l4 * 16) ^ (((lr >> 1) & 7) << 4);
    return *(const short8*)((const char*)lds + buf * 65536 + wr * 16384 + rr * 128 + cb);
  };
  auto LDB = [&](int buf, int nf, int s) -> short8 {
    int rr = (wc & 1) * 64 + nf * 16 + lr;
    int cb = (s * 64 + l4 * 16) ^ (((lr >> 1) & 7) << 4);
    return *(const short8*)((const char*)lds + buf * 65536 + 32768 + (wc >> 1) * 16384 + rr * 128 + cb);
  };

  f32x4 acc[8][4] = {};

  STAGE(0, 0);
  STAGE(1, 1);
  asm volatile("s_waitcnt vmcnt(8)" ::: "memory");
  SBAR();

  for (int kt = 0; kt < 16; ++kt) {
    const int cur = kt & 1;
    short8 a0[4][2], a1[4][2], b[2][2];
#pragma unroll
    for (int i = 0; i < 4; ++i) { a0[i][0] = LDA(cur, i, 0); a0[i][1] = LDA(cur, i, 1); }
#pragma unroll
    for (int n = 0; n < 2; ++n) { b[n][0] = LDB(cur, n, 0); b[n][1] = LDB(cur, n, 1); }
    __builtin_amdgcn_s_setprio(1);
#pragma unroll
    for (int i = 0; i < 4; ++i)
#pragma unroll
      for (int n = 0; n < 2; ++n)
#pragma unroll
        for (int s = 0; s < 2; ++s)
          acc[i][n] = __builtin_amdgcn_mfma_f32_16x16x32_bf16(a0[i][s], b[n][s], acc[i][n], 0, 0, 0);
    __builtin_amdgcn_s_setprio(0);
#pragma unroll
    for (int i = 0; i < 4; ++i) { a1[i][0] = LDA(cur, 4 + i, 0); a1[i][1] = LDA(cur, 4 + i, 1); }
    __builtin_amdgcn_s_setprio(1);
#pragma unroll
    for (int i = 0; i < 4; ++i)
#pragma unroll
      for (int n = 0; n < 2; ++n)
#pragma unroll
        for (int s = 0; s < 2; ++s)
          acc[4 + i][n] = __builtin_amdgcn_mfma_f32_16x16x32_bf16(a1[i][s], b[n][s], acc[4 + i][n], 0, 0, 0);
    __builtin_amdgcn_s_setprio(0);
#pragma unroll
    for (int n = 0; n < 2; ++n) { b[n][0] = LDB(cur, 2 + n, 0); b[n][1] = LDB(cur, 2 + n, 1); }
    __builtin_amdgcn_s_setprio(1);
#pragma unroll
    for (int i = 0; i < 4; ++i)
#pragma unroll
      for (int n = 0; n < 2; ++n)
#pragma unroll
        for (int s = 0; s < 2; ++s)
          acc[4 + i][2 + n] = __builtin_amdgcn_mfma_f32_16x16x32_bf16(a1[i][s], b[n][s], acc[4 + i][2 + n], 0, 0, 0);
#pragma unroll
    for (int i = 0; i < 4; ++i)
#pragma unroll
      for (int n = 0; n < 2; ++n)
#pragma unroll
        for (int s = 0; s < 2; ++s)
          acc[i][2 + n] = __builtin_amdgcn_mfma_f32_16x16x32_bf16(a0[i][s], b[n][s], acc[i][2 + n], 0, 0, 0);
    __builtin_amdgcn_s_setprio(0);

    SBAR();
    if (kt + 2 < 16) {
      STAGE(cur, kt + 2);
      asm volatile("s_waitcnt vmcnt(8)" ::: "memory");
    } else {
      asm volatile("s_waitcnt vmcnt(0)" ::: "memory");
    }
    SBAR();
  }
  #undef STAGE

  u16* out = gparts + (size_t)khalf * 2048 * 4096;
#pragma unroll
  for (int nf = 0; nf < 4; ++nf) {
    int col = n0 + wc * 64 + nf * 16 + lr;
#pragma unroll
    for (int mf = 0; mf < 8; ++mf)
#pragma unroll
      for (int r = 0; r < 4; ++r) {
        int row = m0 + wr * 128 + mf * 16 + l4 * 4 + r;
        out[(size_t)row * 4096 + col] = f2bf(acc[mf][nf][r]);
      }
  }
}

// ---------------- prepQ: query pack + Wq/Wk transposes (runs first) ----------
__global__ __launch_bounds__(256) void prepQ_k(
    const float* __restrict__ query, const float* __restrict__ Wq,
    const float* __restrict__ Wk,
    u16* __restrict__ qry, u16* __restrict__ wqtb, u16* __restrict__ wktb)
{
  __shared__ u16 tile[64][65];
  int blk = blockIdx.x;
  int t = threadIdx.x;
  if (blk < 2048) {
    int cc = t * 4;
    float4 v = *(const float4*)(query + (size_t)blk * 1024 + cc);
    ushort4 o; o.x = f2bf(v.x); o.y = f2bf(v.y); o.z = f2bf(v.z); o.w = f2bf(v.w);
    *(ushort4*)(qry + (size_t)blk * 1024 + cc) = o;
    return;
  }
  const float* src; u16* dst; int tblk;
  if (blk < 2304) { src = Wq; dst = wqtb; tblk = blk - 2048; }
  else            { src = Wk; dst = wktb; tblk = blk - 2304; }
  int tr = (tblk >> 4) * 64, tc = (tblk & 15) * 64;
  int tx = t & 63;
  int ty = (t >> 6) * 16;
#pragma unroll
  for (int i = 0; i < 16; ++i)
    tile[ty + i][tx] = f2bf(src[(size_t)(tr + ty + i) * 1024 + tc + tx]);
  __syncthreads();
#pragma unroll
  for (int i = 0; i < 16; ++i)
    dst[(size_t)(tc + ty + i) * 1024 + tr + tx] = tile[tx][ty + i];
}

// ---------------- prepRG: G gemm + bqwk hidden under remaining packs --------
__global__ __launch_bounds__(256) void prepRG_k(
    const float* __restrict__ pose, const float* __restrict__ h,
    const float* __restrict__ W_ih, const float* __restrict__ W_hh,
    const float* __restrict__ Wv,
    const u16* __restrict__ WkTb, const u16* __restrict__ WqTb,
    const float* __restrict__ bq, const float* __restrict__ Wk,
    u16* __restrict__ xcat, u16* __restrict__ wcat, u16* __restrict__ wvb,
    u16* __restrict__ Gb, float* __restrict__ qkb)
{
  __shared__ __align__(16) u16 As[128 * 32];
  __shared__ __align__(16) u16 Bs[128 * 32];
  const int blk = blockIdx.x;
  const int t = threadIdx.x;
  if (blk < 64) {
    const int lane = t & 63;
    const int w = t >> 6;
    const int wr = w >> 1, wc = w & 1;
    const int m0 = (blk >> 3) * 128, n0 = (blk & 7) * 128;
    const int lr = lane & 15;
    const int lk = (lane >> 4) * 8;
    const int srow = t >> 2;
    const int scol = (t & 3) * 8;
    const u16* gA = WkTb + (size_t)(m0 + srow) * 1024 + scol;
    const u16* gB = WqTb + (size_t)(n0 + srow) * 1024 + scol;
    f32x4 acc[4][4] = {};
    for (int k0 = 0; k0 < 1024; k0 += 32) {
      gl_lds16(gA,                     As + t * 8);
      gl_lds16(gA + (size_t)64 * 1024, As + 2048 + t * 8);
      gl_lds16(gB,                     Bs + t * 8);
      gl_lds16(gB + (size_t)64 * 1024, Bs + 2048 + t * 8);
      gA += 32; gB += 32;
      __syncthreads();
      short8 a[4], b[4];
#pragma unroll
      for (int m = 0; m < 4; ++m)
        a[m] = *(const short8*)(As + (wr * 64 + m * 16 + lr) * 32 + lk);
#pragma unroll
      for (int n = 0; n < 4; ++n)
        b[n] = *(const short8*)(Bs + (wc * 64 + n * 16 + lr) * 32 + lk);
#pragma unroll
      for (int m = 0; m < 4; ++m)
#pragma unroll
        for (int n = 0; n < 4; ++n)
          acc[m][n] = __builtin_amdgcn_mfma_f32_16x16x32_bf16(a[m], b[n], acc[m][n], 0, 0, 0);
      __syncthreads();
    }
#pragma unroll
    for (int n = 0; n < 4; ++n) {
      int col = n0 + wc * 64 + n * 16 + lr;
#pragma unroll
      for (int m = 0; m < 4; ++m)
#pragma unroll
        for (int r = 0; r < 4; ++r) {
          int row = m0 + wr * 64 + m * 16 + (lane >> 4) * 4 + r;
          Gb[(size_t)row * 1024 + col] = f2bf(acc[m][n][r]);
        }
    }
    return;
  }
  if (blk < 68) {
    int n = (blk - 64) * 256 + t;
    float s0 = 0.f, s1 = 0.f;
    for (int j = 0; j < 1024; j += 2) {
      s0 += bq[j]     * Wk[(size_t)j * 1024 + n];
      s1 += bq[j + 1] * Wk[(size_t)(j + 1) * 1024 + n];
    }
    qkb[n] = s0 + s1;
    return;
  }
  int b2 = blk - 68;
  const float* src; u16* dst; int ostride, ooff, base;
  if (b2 < 2048)       { src = pose;  dst = xcat; ostride = 2048; ooff = 0;    base = 0; }
  else if (b2 < 4096)  { src = h;     dst = xcat; ostride = 2048; ooff = 1024; base = 2048; }
  else if (b2 < 8192)  { src = W_ih;  dst = wcat; ostride = 2048; ooff = 0;    base = 4096; }
  else if (b2 < 12288) { src = W_hh;  dst = wcat; ostride = 2048; ooff = 1024; base = 8192; }
  else                 { src = Wv;    dst = wvb;  ostride = 1024; ooff = 0;    base = 12288; }
  int r = b2 - base;
  int cc = t * 4;
  float4 v = *(const float4*)(src + (size_t)r * 1024 + cc);
  ushort4 o; o.x = f2bf(v.x); o.y = f2bf(v.y); o.z = f2bf(v.z); o.w = f2bf(v.w);
  *(ushort4*)(dst + (size_t)r * ostride + ooff + cc) = o;
}

// ---- fused attention + LSTM finish: one wave per batch row -----------------
// Main loop: online softmax over memory rows 1..63 (quad-row, nt loads).
// Epilogue (same wave, no sync needed): LSTM elementwise from gate partials,
// write h_new/c_new, fold h_new row into softmax state via in-register
// s_last = qv . hn, normalize, write bf16 ctx. attst buffer eliminated.
__global__ __launch_bounds__(256) void attnfin_k(
    const float* __restrict__ Qk, const float* __restrict__ mem,
    const u16* __restrict__ gparts, const float* __restrict__ c,
    const float* __restrict__ b_ih, const float* __restrict__ b_hh,
    float* __restrict__ out_h, float* __restrict__ out_c,
    u16* __restrict__ ctxb)
{
  const int t = threadIdx.x;
  const int lane = t & 63;
  const int b = blockIdx.x * 4 + (t >> 6);
  const float* q = Qk + (size_t)b * 1024;
  f32x4 qv[4];
#pragma unroll
  for (int i = 0; i < 4; ++i)
    qv[i] = *(const f32x4*)(q + (i * 64 + lane) * 4);
  const float* mb = mem + (size_t)b * 65536;

  float m_run = -3e38f, l = 0.f;
  f32x4 cx[4] = {};

  // rows 1..60 in quads
  for (int qd = 0; qd < 15; ++qd) {
    const float* r0 = mb + (size_t)(1 + qd * 4) * 1024;
    f32x4 rv[4][4];
    float s[4] = {0.f, 0.f, 0.f, 0.f};
#pragma unroll
    for (int rr = 0; rr < 4; ++rr)
#pragma unroll
      for (int i = 0; i < 4; ++i) {
        rv[rr][i] = __builtin_nontemporal_load(
            (const f32x4*)(r0 + rr * 1024 + (i * 64 + lane) * 4));
        s[rr] += rv[rr][i][0] * qv[i][0] + rv[rr][i][1] * qv[i][1] +
                 rv[rr][i][2] * qv[i][2] + rv[rr][i][3] * qv[i][3];
      }
#pragma unroll
    for (int rr = 0; rr < 4; ++rr) {
#pragma unroll
      for (int off = 32; off; off >>= 1) s[rr] += __shfl_xor(s[rr], off);
      s[rr] *= 0.03125f;
    }
#pragma unroll
    for (int rr = 0; rr < 4; ++rr) {
      if (s[rr] <= m_run + 8.f) {        // defer-max common path
        float e = __expf(s[rr] - m_run);
        l += e;
#pragma unroll
        for (int i = 0; i < 4; ++i) cx[i] += rv[rr][i] * e;
      } else {
        float sc = __expf(m_run - s[rr]);
        m_run = s[rr];
        l = l * sc + 1.f;
#pragma unroll
        for (int i = 0; i < 4; ++i) cx[i] = cx[i] * sc + rv[rr][i];
      }
    }
  }
  // rows 61..63 singles
  for (int r = 61; r <= 63; ++r) {
    const float* row = mb + (size_t)r * 1024;
    f32x4 rv[4];
    float s = 0.f;
#pragma unroll
    for (int i = 0; i < 4; ++i) {
      rv[i] = __builtin_nontemporal_load(
          (const f32x4*)(row + (i * 64 + lane) * 4));
      s += rv[i][0] * qv[i][0] + rv[i][1] * qv[i][1] +
           rv[i][2] * qv[i][2] + rv[i][3] * qv[i][3];
    }
#pragma unroll
    for (int off = 32; off; off >>= 1) s += __shfl_xor(s, off);
    s *= 0.03125f;
    if (s <= m_run + 8.f) {
      float e = __expf(s - m_run);
      l += e;
#pragma unroll
      for (int i = 0; i < 4; ++i) cx[i] += rv[i] * e;
    } else {
      float sc = __expf(m_run - s);
      m_run = s;
      l = l * sc + 1.f;
#pragma unroll
      for (int i = 0; i < 4; ++i) cx[i] = cx[i] * sc + rv[i];
    }
  }

  // ---- epilogue: LSTM for this batch (chunk layout (i*64+lane)*4) ----
  const u16* g0 = gparts + (size_t)b * 4096;
  const u16* g1 = g0 + (size_t)2048 * 4096;
  f32x4 hn[4];
  float s_last = 0.f;
#pragma unroll
  for (int i = 0; i < 4; ++i) {
    const int base = (i * 64 + lane) * 4;
    float gsum[4][4];
#pragma unroll
    for (int gi = 0; gi < 4; ++gi) {
      ushort4 a = *(const ushort4*)(g0 + gi * 1024 + base);
      ushort4 bb = *(const ushort4*)(g1 + gi * 1024 + base);
      float4 bi = *(const float4*)(b_ih + gi * 1024 + base);
      float4 bh = *(const float4*)(b_hh + gi * 1024 + base);
      gsum[gi][0] = bf2f(a.x) + bf2f(bb.x) + bi.x + bh.x;
      gsum[gi][1] = bf2f(a.y) + bf2f(bb.y) + bi.y + bh.y;
      gsum[gi][2] = bf2f(a.z) + bf2f(bb.z) + bi.z + bh.z;
      gsum[gi][3] = bf2f(a.w) + bf2f(bb.w) + bi.w + bh.w;
    }
    float4 cv = *(const float4*)(c + (size_t)b * 1024 + base);
    float cvs[4] = {cv.x, cv.y, cv.z, cv.w};
    f32x4 cnv;
#pragma unroll
    for (int j = 0; j < 4; ++j) {
      float si = 1.f / (1.f + __expf(-gsum[0][j]));
      float sf = 1.f / (1.f + __expf(-gsum[1][j]));
      float so = 1.f / (1.f + __expf(-gsum[3][j]));
      float tg = 2.f / (1.f + __expf(-2.f * gsum[2][j])) - 1.f;
      float cn = sf * cvs[j] + si * tg;
      float tc2 = 2.f / (1.f + __expf(-2.f * cn)) - 1.f;
      cnv[j] = cn;
      hn[i][j] = so * tc2;
    }
    *(f32x4*)(out_c + (size_t)b * 1024 + base) = cnv;
    *(f32x4*)(out_h + (size_t)b * 1024 + base) = hn[i];
    s_last += qv[i][0] * hn[i][0] + qv[i][1] * hn[i][1] +
              qv[i][2] * hn[i][2] + qv[i][3] * hn[i][3];
  }
#pragma unroll
  for (int off = 32; off; off >>= 1) s_last += __shfl_xor(s_last, off);
  s_last *= 0.03125f;

  if (s_last <= m_run + 8.f) {
    float e = __expf(s_last - m_run);
    l += e;
#pragma unroll
    for (int i = 0; i < 4; ++i) cx[i] += hn[i] * e;
  } else {
    float sc = __expf(m_run - s_last);
    l = l * sc + 1.f;
#pragma unroll
    for (int i = 0; i < 4; ++i) cx[i] = cx[i] * sc + hn[i];
  }
  float inv = 1.f / l;
#pragma unroll
  for (int i = 0; i < 4; ++i) {
    ushort4 o;
    o.x = f2bf(cx[i][0] * inv); o.y = f2bf(cx[i][1] * inv);
    o.z = f2bf(cx[i][2] * inv); o.w = f2bf(cx[i][3] * inv);
    *(ushort4*)(ctxb + (size_t)b * 1024 + (i * 64 + lane) * 4) = o;
  }
}

extern "C" void kernel_launch(void* const* d_in, const int* in_sizes, int n_in,
                              void* d_out, int out_size, void* d_ws, size_t ws_size,
                              hipStream_t stream) {
  const int Bb = 2048, Hh = 1024;
  const float* pose  = (const float*)d_in[0];
  const float* query = (const float*)d_in[1];
  const float* h     = (const float*)d_in[2];
  const float* c     = (const float*)d_in[3];
  const float* mem   = (const float*)d_in[4];
  const float* W_ih  = (const float*)d_in[5];
  const float* W_hh  = (const float*)d_in[6];
  const float* b_ih  = (const float*)d_in[7];
  const float* b_hh  = (const float*)d_in[8];
  const float* Wq    = (const float*)d_in[9];
  const float* bq    = (const float*)d_in[10];
  const float* Wk    = (const float*)d_in[11];
  // d_in[12] = bk: m-independent score shift, cancels in softmax
  const float* Wv    = (const float*)d_in[13];
  const float* bv    = (const float*)d_in[14];

  float* out_att = (float*)d_out;
  float* out_h   = out_att + (size_t)Bb * Hh;
  float* out_c   = out_h + (size_t)Bb * Hh;

  char* wp = (char*)d_ws;
  auto alloc = [&](size_t bytes) {
    char* p = wp; wp += (bytes + 255) & ~(size_t)255; return p;
  };
  u16*   Xcat  = (u16*)alloc((size_t)2048 * 2048 * 2);   // 8 MB
  u16*   Wcat  = (u16*)alloc((size_t)4096 * 2048 * 2);   // 16 MB
  u16*   Qryb  = (u16*)alloc((size_t)2048 * 1024 * 2);   // 4 MB
  u16*   WqTb  = (u16*)alloc((size_t)1024 * 1024 * 2);   // 2 MB
  u16*   WkTb  = (u16*)alloc((size_t)1024 * 1024 * 2);   // 2 MB
  u16*   Gb    = (u16*)alloc((size_t)1024 * 1024 * 2);   // 2 MB
  u16*   Wvb   = (u16*)alloc((size_t)1024 * 1024 * 2);   // 2 MB
  u16*   gparts= (u16*)alloc((size_t)2 * 2048 * 4096 * 2); // 32 MB
  float* qkb   = (float*)alloc((size_t)1024 * 4);
  float* Qk    = (float*)alloc((size_t)2048 * 1024 * 4); // 8 MB
  u16*   ctxb  = (u16*)alloc((size_t)2048 * 1024 * 2);   // 4 MB

  // 1. prepQ: query pack + Wq/Wk transposes (feeds G)
  prepQ_k<<<2560, 256, 0, stream>>>(query, Wq, Wk, Qryb, WqTb, WkTb);

  // 2. prepRG: G gemm (64 blk) + bqwk (4 blk) hidden under packs
  prepRG_k<<<13380, 256, 0, stream>>>(pose, h, W_ih, W_hh, Wv,
                                      WkTb, WqTb, bq, Wk,
                                      Xcat, Wcat, Wvb, Gb, qkb);

  // 3. Qk = query @ G^T + bq@Wk  (64x128 tiles -> 256 blocks, full GPU)
  gemm64_k<<<dim3(8, 32), 256, 0, stream>>>(
      Qryb, Gb, Qk, nullptr, qkb, 2048, 1024, 1024);

  // 4. gates: 256^2 8-wave counted-vmcnt kernel (bank-uniform swizzle)
  gates8_k<<<256, 512, 0, stream>>>(Xcat, Wcat, gparts);

  // 5. fused attention (rows 1..63) + LSTM + h_new fold + ctx (one launch)
  attnfin_k<<<512, 256, 0, stream>>>(Qk, mem, gparts, c, b_ih, b_hh,
                                     out_h, out_c, ctxb);

  // 6. attended = ctx @ Wv^T + bv  (64x128 tiles -> 256 blocks, full GPU)
  gemm64_k<<<dim3(8, 32), 256, 0, stream>>>(
      ctxb, Wvb, out_att, nullptr, bv, 2048, 1024, 1024);
}